// Round 12
// baseline (199.645 us; speedup 1.0000x reference)
//
#include <hip/hip_runtime.h>
#include <hip/hip_bf16.h>

typedef __attribute__((ext_vector_type(8))) short bf16x8;
typedef __attribute__((ext_vector_type(4))) float f32x4;

#define MFMA16(A, B, C) __builtin_amdgcn_mfma_f32_16x16x32_bf16(A, B, C, 0, 0, 0)

__device__ __forceinline__ unsigned short f2bf(float f) {
    unsigned int u = __float_as_uint(f);
    u += 0x7fffu + ((u >> 16) & 1u);
    return (unsigned short)(u >> 16);
}
__device__ __forceinline__ float bf2f(unsigned short h) {
    return __uint_as_float(((unsigned int)h) << 16);
}
__device__ __forceinline__ unsigned int pack_bf2(float lo, float hi) {
    __hip_bfloat162 h = __float22bfloat162_rn(make_float2(lo, hi)); // v_cvt_pk_bf16_f32
    return *reinterpret_cast<unsigned int*>(&h);
}

__device__ __forceinline__ void gload_lds16(const void* g, void* l) {
    __builtin_amdgcn_global_load_lds(
        (__attribute__((address_space(1))) unsigned int*)g,
        (__attribute__((address_space(3))) unsigned int*)l, 16, 0, 0);
}

// LDS swizzle for [128 rows][64 bf16] regions (128 B/row): XOR chunk with row&7.
__device__ __forceinline__ int swz128(int by) {
    return by ^ (((by >> 7) & 7) << 4);
}

// ---------------------------------------------------------------- fused converts (1 launch)
__global__ void cvt_all_kernel(const float* __restrict__ x,  const float* __restrict__ wq,
                               const float* __restrict__ wk, const float* __restrict__ wv,
                               const float* __restrict__ wo,
                               unsigned short* __restrict__ xb,
                               unsigned short* __restrict__ wqkv,
                               unsigned short* __restrict__ wob) {
    const int i = blockIdx.x * 256 + threadIdx.x; // 0 .. 4718591 (float4 units)
    const float* src;
    unsigned short* dst;
    int off;
    if (i < 2097152)      { src = x;  dst = xb;   off = i; }
    else if (i < 3145728) { src = wq; dst = wqkv; off = i - 2097152; }
    else if (i < 3407872) { src = wk; dst = wqkv + (size_t)2048 * 2048; off = i - 3145728; }
    else if (i < 3670016) { src = wv; dst = wqkv + (size_t)2560 * 2048; off = i - 3407872; }
    else                  { src = wo; dst = wob;  off = i - 3670016; }
    const float4 v = ((const float4*)src)[off];
    uint2 o;
    o.x = pack_bf2(v.x, v.y);
    o.y = pack_bf2(v.z, v.w);
    ((uint2*)dst)[off] = o;
}

// ---------------------------------------------------------------- doc starts
__global__ void docstart_kernel(const int* __restrict__ sid, int* __restrict__ ds) {
    const int i = blockIdx.x * 256 + threadIdx.x; // 0..4095
    const int b = i >> 11, s = i & 2047;
    const int* row = sid + b * 2048;
    const int v = row[s];
    int lo = 0, hi = s;
    while (lo < hi) { const int mid = (lo + hi) >> 1; if (row[mid] < v) lo = mid + 1; else hi = mid; }
    ds[i] = lo;
}

// ---------------------------------------------------------------- QKV 256x256 8-phase GEMM (round-6/9 verified, FROZEN)
#define QKV_K 2048
#define QKV_NT 32
__global__ __launch_bounds__(512, 2) void gemm_qkv8(
    const unsigned short* __restrict__ A,
    const unsigned short* __restrict__ B,
    unsigned short* __restrict__ oq,
    unsigned short* __restrict__ ok,
    unsigned short* __restrict__ ov)
{
    __shared__ __align__(16) unsigned short S[2][2][2][8192]; // 128 KiB
    const int tid = threadIdx.x, lane = tid & 63, w = tid >> 6;
    const int wr = w >> 2, wc = w & 3;
    const int lr = lane & 15, lc = lane >> 4;

    // XCD swizzle over 192 blocks (192 % 8 == 0)
    int bid = blockIdx.x;
    bid = (bid & 7) * 24 + (bid >> 3);
    const int m0 = (bid / 12) * 256, n0 = (bid % 12) * 256;

    // staging geometry: linear LDS dest, inverse-swizzled global source (rule #21)
    const int o0 = (w << 11) + (lane << 4);
    const int o1 = o0 + 1024;
    const int v0 = swz128(o0), v1 = swz128(o1);
    const int r0 = v0 >> 7, c0 = (v0 & 127) >> 1;
    const int r1 = v1 >> 7, c1 = (v1 & 127) >> 1;
    const size_t aoff0 = (size_t)(m0 + r0) * QKV_K + c0;
    const size_t aoff1 = (size_t)(m0 + r1) * QKV_K + c1;
    const size_t boff0 = (size_t)(n0 + r0) * QKV_K + c0;
    const size_t boff1 = (size_t)(n0 + r1) * QKV_K + c1;
    const int d0 = o0 >> 1, d1 = o1 >> 1;

    f32x4 acc[2][2][4][2];
#pragma unroll
    for (int a = 0; a < 2; a++)
#pragma unroll
        for (int bq = 0; bq < 2; bq++)
#pragma unroll
            for (int i = 0; i < 4; i++)
#pragma unroll
                for (int j = 0; j < 2; j++) acc[a][bq][i][j] = (f32x4){0.f, 0.f, 0.f, 0.f};

    bf16x8 Af[4][2], Bf0[2][2], Bf1[2][2];

    auto STAGE_A = [&](int bf, int h, int kt) {
        gload_lds16(A + aoff0 + (size_t)h * 128 * QKV_K + (size_t)kt * 64, &S[bf][0][h][d0]);
        gload_lds16(A + aoff1 + (size_t)h * 128 * QKV_K + (size_t)kt * 64, &S[bf][0][h][d1]);
    };
    auto STAGE_B = [&](int bf, int h, int kt) {
        gload_lds16(B + boff0 + (size_t)h * 128 * QKV_K + (size_t)kt * 64, &S[bf][1][h][d0]);
        gload_lds16(B + boff1 + (size_t)h * 128 * QKV_K + (size_t)kt * 64, &S[bf][1][h][d1]);
    };
    auto LDA = [&](int bf, int mh) {
#pragma unroll
        for (int i = 0; i < 4; i++)
#pragma unroll
            for (int kh = 0; kh < 2; kh++) {
                const int by = swz128(((wr * 64 + i * 16 + lr) << 7) + (kh << 6) + (lc << 4));
                Af[i][kh] = *(const bf16x8*)((const char*)&S[bf][0][mh][0] + by);
            }
    };
    auto LDB = [&](int bf, int nh, bf16x8 (&Bf)[2][2]) {
#pragma unroll
        for (int j = 0; j < 2; j++)
#pragma unroll
            for (int kh = 0; kh < 2; kh++) {
                const int by = swz128(((wc * 32 + j * 16 + lr) << 7) + (kh << 6) + (lc << 4));
                Bf[j][kh] = *(const bf16x8*)((const char*)&S[bf][1][nh][0] + by);
            }
    };
    auto QUAD = [&](f32x4 (&ac)[4][2], bf16x8 (&Bf)[2][2]) {
        __builtin_amdgcn_s_setprio(1);
#pragma unroll
        for (int i = 0; i < 4; i++)
#pragma unroll
            for (int j = 0; j < 2; j++)
#pragma unroll
                for (int kh = 0; kh < 2; kh++)
                    ac[i][j] = MFMA16(Af[i][kh], Bf[j][kh], ac[i][j]);
        __builtin_amdgcn_s_setprio(0);
    };

#define BAR() __builtin_amdgcn_s_barrier()
#define LGKM0() asm volatile("s_waitcnt lgkmcnt(0)" ::: "memory")

    // ---- prologue: tile0 (A0,A1,B0,B1)->buf0; A0[1],B1[1],A1[1]->buf1; drain to 3
    STAGE_A(0, 0, 0); STAGE_A(0, 1, 0); STAGE_B(0, 0, 0); STAGE_B(0, 1, 0);
    STAGE_A(1, 0, 1); STAGE_B(1, 1, 1); STAGE_A(1, 1, 1);
    asm volatile("s_waitcnt vmcnt(6)" ::: "memory");
    BAR();

    auto GROUP = [&](int g, int bf) {
        // ph1: quadrant (0,0); stage B0[g+1] -> other buf
        LDA(bf, 0); LDB(bf, 0, Bf0);
        if (g + 1 < QKV_NT) STAGE_B(bf ^ 1, 0, g + 1);
        BAR(); LGKM0();
        QUAD(acc[0][0], Bf0);
        BAR();
        // ph2: (0,1); stage A0[g+2] -> current buf
        LDB(bf, 1, Bf1);
        if (g + 2 < QKV_NT) STAGE_A(bf, 0, g + 2);
        BAR(); LGKM0();
        QUAD(acc[0][1], Bf1);
        BAR();
        // ph3: (1,1); stage B1[g+2] -> current buf
        LDA(bf, 1);
        if (g + 2 < QKV_NT) STAGE_B(bf, 1, g + 2);
        BAR(); LGKM0();
        QUAD(acc[1][1], Bf1);
        BAR();
        // ph4: (1,0); stage A1[g+2] -> current buf
        if (g + 2 < QKV_NT) STAGE_A(bf, 1, g + 2);
        BAR();
        QUAD(acc[1][0], Bf0);
        if (g == QKV_NT - 2) { asm volatile("s_waitcnt vmcnt(0)" ::: "memory"); }
        else                 { asm volatile("s_waitcnt vmcnt(6)" ::: "memory"); }
        BAR();
    };

#pragma unroll 1
    for (int g = 0; g < QKV_NT; g += 2) {
        GROUP(g, 0);
        GROUP(g + 1, 1);
    }

    // ---- epilogue: scatter into Q:(B,32,S,64), K/V:(B,8,S,64) bf16
#pragma unroll
    for (int mh = 0; mh < 2; mh++)
#pragma unroll
        for (int nh = 0; nh < 2; nh++)
#pragma unroll
            for (int i = 0; i < 4; i++)
#pragma unroll
                for (int j = 0; j < 2; j++) {
                    const int n = n0 + nh * 128 + wc * 32 + j * 16 + lr;
                    const int d = n & 63;
                    const int hh6 = n >> 6;
#pragma unroll
                    for (int r = 0; r < 4; r++) {
                        const int m = m0 + mh * 128 + wr * 64 + i * 16 + lc * 4 + r;
                        const int bb = m >> 11, s = m & 2047;
                        const unsigned short val = f2bf(acc[mh][nh][i][j][r]);
                        if (n < 2048) {
                            oq[((((size_t)bb * 32 + hh6) * 2048 + s) << 6) + d] = val;
                        } else if (n < 2560) {
                            ok[((((size_t)bb * 8 + (hh6 - 32)) * 2048 + s) << 6) + d] = val;
                        } else {
                            ov[((((size_t)bb * 8 + (hh6 - 40)) * 2048 + s) << 6) + d] = val;
                        }
                    }
                }
}
#undef BAR
#undef LGKM0

// ---------------------------------------------------------------- RoPE, vectorized 4 pairs/thread
__global__ void rope_kernel(unsigned short* __restrict__ Qb,
                            unsigned short* __restrict__ Kb,
                            const float* __restrict__ fc)
{
    const int NQ = 64 * 2048 * 8; // Q thread count (2*32 heads)
    int j = blockIdx.x * 256 + threadIdx.x;
    unsigned short* base;
    if (j < NQ) base = Qb;
    else { base = Kb; j -= NQ; }
    const int g = j & 7, s = (j >> 3) & 2047, bh = j >> 14;
    const size_t off = (((size_t)bh * 2048 + s) << 6) + g * 8;
    uint4 u = *(uint4*)&base[off];
    const float4 cs0 = *(const float4*)&fc[((s << 5) + g * 4) << 1];       // c0 s0 c1 s1
    const float4 cs1 = *(const float4*)&fc[(((s << 5) + g * 4) << 1) + 4]; // c2 s2 c3 s3
    unsigned int* uw = (unsigned int*)&u;
    float c[4] = {cs0.x, cs0.z, cs1.x, cs1.z};
    float sn[4] = {cs0.y, cs0.w, cs1.y, cs1.w};
#pragma unroll
    for (int q = 0; q < 4; q++) {
        const float t0 = bf2f((unsigned short)(uw[q] & 0xffffu));
        const float t1 = bf2f((unsigned short)(uw[q] >> 16));
        uw[q] = pack_bf2(fmaf(t0, c[q], -t1 * sn[q]), fmaf(t0, sn[q], t1 * c[q]));
    }
    *(uint4*)&base[off] = u;
}

// ---------------------------------------------------------------- bt-GEMM (m97) for out-proj + chunk-XOR LDS swizzle
// sA/sB [128][32] bf16: bank = (16r + 4c) mod 32 -> rows alias 8-way on ds_read_b128.
// Involution c_phys = c ^ ((r>>1)&3): bank = (16r + 4(c^((r>>1)&3))) mod 32 -> 32 banks
// x 2 lanes = free. Both-sides (rule #21): inverse-swizzled global source + XOR'd read.
template <int EPI>
__global__ __launch_bounds__(256) void gemm_bt(
    const unsigned short* __restrict__ A,
    const unsigned short* __restrict__ B,
    int K, int N,
    unsigned short* __restrict__ oq,
    unsigned short* __restrict__ ok,
    unsigned short* __restrict__ ov,
    float* __restrict__ of)
{
    __shared__ __align__(16) unsigned short sA[128 * 32];
    __shared__ __align__(16) unsigned short sB[128 * 32];
    const int tid = threadIdx.x;
    const int lane = tid & 63, wave = tid >> 6;
    const int wr = wave >> 1, wc = wave & 1;
    const int lr = lane & 15, lc = lane >> 4;

    int bid = blockIdx.y * gridDim.x + blockIdx.x;
    const int cpx = (gridDim.x * gridDim.y) >> 3;
    bid = (bid & 7) * cpx + (bid >> 3);
    const int m0 = (bid / gridDim.x) * 128, n0 = (bid % gridDim.x) * 128;

    f32x4 acc[4][4];
#pragma unroll
    for (int i = 0; i < 4; i++)
#pragma unroll
        for (int j = 0; j < 4; j++) acc[i][j] = (f32x4){0.f, 0.f, 0.f, 0.f};

    const int u0 = tid, u1 = tid + 256;
    const int su0 = (u0 & 3) ^ ((u0 >> 3) & 3); // inverse-swizzled source chunk
    const int su1 = (u1 & 3) ^ ((u1 >> 3) & 3);
    const int cX = (lc ^ ((lr >> 1) & 3)) * 8;  // swizzled read chunk (elements)
    for (int k0 = 0; k0 < K; k0 += 32) {
        __syncthreads();
        gload_lds16(A + (size_t)(m0 + (u0 >> 2)) * K + k0 + su0 * 8, &sA[u0 * 8]);
        gload_lds16(A + (size_t)(m0 + (u1 >> 2)) * K + k0 + su1 * 8, &sA[u1 * 8]);
        gload_lds16(B + (size_t)(n0 + (u0 >> 2)) * K + k0 + su0 * 8, &sB[u0 * 8]);
        gload_lds16(B + (size_t)(n0 + (u1 >> 2)) * K + k0 + su1 * 8, &sB[u1 * 8]);
        __syncthreads();
        bf16x8 af[4], bfv[4];
#pragma unroll
        for (int i = 0; i < 4; i++) {
            af[i]  = *(const bf16x8*)&sA[(wr * 64 + i * 16 + lr) * 32 + cX];
            bfv[i] = *(const bf16x8*)&sB[(wc * 64 + i * 16 + lr) * 32 + cX];
        }
        __builtin_amdgcn_s_setprio(1);
#pragma unroll
        for (int i = 0; i < 4; i++)
#pragma unroll
            for (int j = 0; j < 4; j++) acc[i][j] = MFMA16(af[i], bfv[j], acc[i][j]);
        __builtin_amdgcn_s_setprio(0);
    }

    if (EPI == 0) {
#pragma unroll
        for (int i = 0; i < 4; i++) {
#pragma unroll
            for (int j = 0; j < 4; j++) {
                const int n = n0 + wc * 64 + j * 16 + lr;
                const int d = n & 63;
#pragma unroll
                for (int r = 0; r < 4; r++) {
                    const int m = m0 + wr * 64 + i * 16 + lc * 4 + r;
                    const int bb = m >> 11, s = m & 2047;
                    const unsigned short val = f2bf(acc[i][j][r]);
                    if (n < 2048) {
                        const int hh = n >> 6;
                        oq[((((size_t)bb * 32 + hh) * 2048 + s) << 6) + d] = val;
                    } else if (n < 2560) {
                        const int hh = (n >> 6) - 32;
                        ok[((((size_t)bb * 8 + hh) * 2048 + s) << 6) + d] = val;
                    } else {
                        const int hh = (n >> 6) - 40;
                        ov[((((size_t)bb * 8 + hh) * 2048 + s) << 6) + d] = val;
                    }
                }
            }
        }
    } else {
#pragma unroll
        for (int i = 0; i < 4; i++)
#pragma unroll
            for (int j = 0; j < 4; j++)
#pragma unroll
                for (int r = 0; r < 4; r++) {
                    const int m = m0 + wr * 64 + i * 16 + lc * 4 + r;
                    const int n = n0 + wc * 64 + j * 16 + lr;
                    of[(size_t)m * N + n] = acc[i][j][r];
                }
    }
}

// ---------------------------------------------------------------- flash attention v6: QBLK=128 + T5 setprio + exp2 + T13 defer-max
__global__ __launch_bounds__(512) void attn_kernel(
    const unsigned short* __restrict__ Q,
    const unsigned short* __restrict__ K,
    const unsigned short* __restrict__ V,
    const int* __restrict__ dstart,
    unsigned short* __restrict__ AO)
{
    const int qt = 15 - blockIdx.x; // heavy blocks first
    const int h = blockIdx.y, b = blockIdx.z;
    const int kvh = h >> 2;
    const int tid = threadIdx.x, lane = tid & 63, wave = tid >> 6;
    const int lr = lane & 15, lc = lane >> 4;
    const int q0 = qt * 128;
    const int qw = q0 + wave * 16;

    __shared__ __align__(16) unsigned short sK[2][64 * 64];   // chunk-XOR swizzled
    __shared__ __align__(16) unsigned short sVt[2][64][72];   // V^T; flat [128][72] in epilogue

    const unsigned short* Qh = Q + (((size_t)b * 32 + h) * 2048) * 64;
    const unsigned short* Kh = K + (((size_t)b * 8 + kvh) * 2048) * 64;
    const unsigned short* Vh = V + (((size_t)b * 8 + kvh) * 2048) * 64;

    const bf16x8 qf0 = *(const bf16x8*)&Qh[(size_t)(qw + lr) * 64 + lc * 8];
    const bf16x8 qf1 = *(const bf16x8*)&Qh[(size_t)(qw + lr) * 64 + 32 + lc * 8];

    const int qglob = qw + lr;
    const int dsl = dstart[b * 2048 + qglob];
    const int ds_wmin = dstart[b * 2048 + qw];
    const int t0 = dstart[b * 2048 + q0] & ~63;

    const int w8 = wave * 8;
    const int kr = tid >> 3, kc = tid & 7; // 512 threads cover the 64x64 K tile

    auto STAGE_K = [&](int t, int c) {
        gload_lds16(Kh + (size_t)(t + kr) * 64 + ((kc ^ (kr & 7)) * 8), &sK[c][tid * 8]);
    };
    auto WRITE_V = [&](const uint4& va, int c) {
        const unsigned short* pa = (const unsigned short*)&va;
#pragma unroll
        for (int e = 0; e < 8; e++) sVt[c][w8 + e][lane] = pa[e];
    };

    // softmax in exp2 domain: S_scaled = S * 0.125 * log2(e)
    const float SC2 = 0.125f * 1.4426950408889634f;

    float mrow = -1e30f, lrow = 0.f;
    f32x4 oacc[4];
#pragma unroll
    for (int j = 0; j < 4; j++) oacc[j] = (f32x4){0.f, 0.f, 0.f, 0.f};

    // ---- prologue: stage tile t0 into buf 0
    STAGE_K(t0, 0);
    {
        const uint4 va = *(const uint4*)&Vh[(size_t)(t0 + lane) * 64 + w8];
        asm volatile("s_waitcnt vmcnt(0)" ::: "memory");
        WRITE_V(va, 0);
    }
    __syncthreads();

    int cb = 0;
    for (int t = t0; t < q0 + 128; t += 64, cb ^= 1) {
        const bool more = (t < q0 + 64); // block-uniform
        uint4 va;
        if (more) {
            STAGE_K(t + 64, cb ^ 1);
            va = *(const uint4*)&Vh[(size_t)(t + 64 + lane) * 64 + w8];
        }
        const bool act = !(t > qw + 15 || t + 63 < ds_wmin); // wave-uniform
        union { unsigned int w[4]; bf16x8 v; } B0, B1;

        if (act) {
            // --- QK^T swapped: C[k][q], k = kk*16 + lc*4 + r, q = qw + lr
            f32x4 sc[4];
            __builtin_amdgcn_s_setprio(1);
#pragma unroll
            for (int kk = 0; kk < 4; kk++) {
                const int krow = kk * 16 + lr;
                const bf16x8 kf0 = *(const bf16x8*)&sK[cb][krow * 64 + ((lc ^ (lr & 7)) * 8)];
                const bf16x8 kf1 = *(const bf16x8*)&sK[cb][krow * 64 + (((4 + lc) ^ (lr & 7)) * 8)];
                f32x4 a = (f32x4){0.f, 0.f, 0.f, 0.f};
                a = MFMA16(kf0, qf0, a);
                a = MFMA16(kf1, qf1, a);
                sc[kk] = a;
            }
            __builtin_amdgcn_s_setprio(0);
            // --- mask + scale (exp2 domain) + in-lane softmax
            float vmax = -3e38f;
#pragma unroll
            for (int kk = 0; kk < 4; kk++)
#pragma unroll
                for (int r = 0; r < 4; r++) {
                    const int kpos = t + kk * 16 + lc * 4 + r;
                    const bool okm = (kpos <= qglob) && (kpos >= dsl);
                    sc[kk][r] = okm ? sc[kk][r] * SC2 : -3e38f;
                    vmax = fmaxf(vmax, sc[kk][r]);
                }
            vmax = fmaxf(vmax, __shfl_xor(vmax, 16));
            vmax = fmaxf(vmax, __shfl_xor(vmax, 32));
            // T13 defer-max: skip O/l rescale while vmax <= mrow + 8 (P bounded by 2^8)
            if (!__all(vmax <= mrow + 8.f)) {
                const float mnew = fmaxf(mrow, vmax);
                const float corr = __builtin_exp2f(mrow - mnew);
                mrow = mnew;
                lrow *= corr;
#pragma unroll
                for (int j = 0; j < 4; j++)
#pragma unroll
                    for (int r = 0; r < 4; r++) oacc[j][r] *= corr;
            }

            float rsum = 0.f;
            unsigned int pk[4][2];
#pragma unroll
            for (int kk = 0; kk < 4; kk++) {
                const float p0 = __builtin_exp2f(sc[kk][0] - mrow);
                const float p1 = __builtin_exp2f(sc[kk][1] - mrow);
                const float p2 = __builtin_exp2f(sc[kk][2] - mrow);
                const float p3 = __builtin_exp2f(sc[kk][3] - mrow);
                rsum += (p0 + p1) + (p2 + p3);
                pk[kk][0] = pack_bf2(p0, p1);
                pk[kk][1] = pack_bf2(p2, p3);
            }
            rsum += __shfl_xor(rsum, 16);
            rsum += __shfl_xor(rsum, 32);
            lrow += rsum;

            // --- redistribute P -> PV B-frags (shuffle both kk candidates, select by dest lc>>1)
            const int srcEven = 32 * (lc & 1) + lr;
            const int srcOdd  = srcEven + 16;
            const bool hiKK = (lc & 2) != 0;
            unsigned int a, c;
            a = __shfl(pk[0][0], srcEven); c = __shfl(pk[1][0], srcEven); B0.w[0] = hiKK ? c : a;
            a = __shfl(pk[0][1], srcEven); c = __shfl(pk[1][1], srcEven); B0.w[1] = hiKK ? c : a;
            a = __shfl(pk[0][0], srcOdd);  c = __shfl(pk[1][0], srcOdd);  B0.w[2] = hiKK ? c : a;
            a = __shfl(pk[0][1], srcOdd);  c = __shfl(pk[1][1], srcOdd);  B0.w[3] = hiKK ? c : a;
            a = __shfl(pk[2][0], srcEven); c = __shfl(pk[3][0], srcEven); B1.w[0] = hiKK ? c : a;
            a = __shfl(pk[2][1], srcEven); c = __shfl(pk[3][1], srcEven); B1.w[1] = hiKK ? c : a;
            a = __shfl(pk[2][0], srcOdd);  c = __shfl(pk[3][0], srcOdd);  B1.w[2] = hiKK ? c : a;
            a = __shfl(pk[2][1], srcOdd);  c = __shfl(pk[3][1], srcOdd);  B1.w[3] = hiKK ? c : a;
        }

        if (more) {
            asm volatile("s_waitcnt vmcnt(0)" ::: "memory"); // V(t+64) regs + K(t+64) LDS landed
            WRITE_V(va, cb ^ 1);
        }

        if (act) {
            // --- PV: O^T = V^T x P^T, C[d][q]: d = j*16 + lc*4 + r, q = qw + lr
            __builtin_amdgcn_s_setprio(1);
#pragma unroll
            for (int j = 0; j < 4; j++) {
                const bf16x8 a0 = *(const bf16x8*)&sVt[cb][j * 16 + lr][lc * 8];
                const bf16x8 a1 = *(const bf16x8*)&sVt[cb][j * 16 + lr][32 + lc * 8];
                oacc[j] = MFMA16(a0, B0.v, oacc[j]);
                oacc[j] = MFMA16(a1, B1.v, oacc[j]);
            }
            __builtin_amdgcn_s_setprio(0);
        }
        __syncthreads();
    }

    // --- epilogue: transpose via LDS (sVt viewed as flat [128][72]), coalesced stores
    unsigned short (*E)[72] = (unsigned short (*)[72])&sVt[0][0][0];
    const float inv = 1.0f / lrow;
#pragma unroll
    for (int j = 0; j < 4; j++)
#pragma unroll
        for (int p = 0; p < 2; p++) {
            const unsigned int w = pack_bf2(oacc[j][2 * p] * inv, oacc[j][2 * p + 1] * inv);
            *(unsigned int*)&E[wave * 16 + lr][j * 16 + lc * 4 + 2 * p] = w;
        }
    __syncthreads();
#pragma unroll
    for (int half = 0; half < 2; half++) {
        const int c = lane + 64 * half;
        const int row = c >> 3, ch = c & 7;
        const uint4 o = *(const uint4*)&E[wave * 16 + row][ch * 8];
        *(uint4*)&AO[((size_t)b * 2048 + qw + row) * 2048 + h * 64 + ch * 8] = o;
    }
}

// ---------------------------------------------------------------- host
extern "C" void kernel_launch(void* const* d_in, const int* in_sizes, int n_in,
                              void* d_out, int out_size, void* d_ws, size_t ws_size,
                              hipStream_t stream) {
    const float* x  = (const float*)d_in[0];
    const float* fc = (const float*)d_in[1];
    const int* sid  = (const int*)d_in[2];
    const float* wq = (const float*)d_in[3];
    const float* wk = (const float*)d_in[4];
    const float* wv = (const float*)d_in[5];
    const float* wo = (const float*)d_in[6];
    float* out = (float*)d_out;

    unsigned short* xb   = (unsigned short*)d_ws;
    unsigned short* wqkv = xb + (size_t)4096 * 2048;
    unsigned short* wob  = wqkv + (size_t)3072 * 2048;
    unsigned short* Qb   = wob + (size_t)2048 * 2048;
    unsigned short* Kb   = Qb + (size_t)2 * 32 * 2048 * 64;
    unsigned short* Vb   = Kb + (size_t)2 * 8 * 2048 * 64;
    unsigned short* AO   = Vb + (size_t)2 * 8 * 2048 * 64;
    int* dstart = (int*)(AO + (size_t)4096 * 2048);

    cvt_all_kernel<<<18432, 256, 0, stream>>>(x, wq, wk, wv, wo, xb, wqkv, wob);
    docstart_kernel<<<16, 256, 0, stream>>>(sid, dstart);
    gemm_qkv8<<<dim3(192), 512, 0, stream>>>(xb, wqkv, Qb, Kb, Vb);
    rope_kernel<<<5120, 256, 0, stream>>>(Qb, Kb, fc);
    attn_kernel<<<dim3(16, 32, 2), 512, 0, stream>>>(Qb, Kb, Vb, dstart, AO);
    gemm_bt<1><<<dim3(16, 32), 256, 0, stream>>>(AO, wob, 2048, 2048, nullptr, nullptr, nullptr, out);
}

// Round 13
// 197.687 us; speedup vs baseline: 1.0099x; 1.0099x over previous
//
#include <hip/hip_runtime.h>
#include <hip/hip_bf16.h>

typedef __attribute__((ext_vector_type(8))) short bf16x8;
typedef __attribute__((ext_vector_type(4))) float f32x4;

#define MFMA16(A, B, C) __builtin_amdgcn_mfma_f32_16x16x32_bf16(A, B, C, 0, 0, 0)

__device__ __forceinline__ unsigned short f2bf(float f) {
    unsigned int u = __float_as_uint(f);
    u += 0x7fffu + ((u >> 16) & 1u);
    return (unsigned short)(u >> 16);
}
__device__ __forceinline__ float bf2f(unsigned short h) {
    return __uint_as_float(((unsigned int)h) << 16);
}
__device__ __forceinline__ unsigned int pack_bf2(float lo, float hi) {
    __hip_bfloat162 h = __float22bfloat162_rn(make_float2(lo, hi)); // v_cvt_pk_bf16_f32
    return *reinterpret_cast<unsigned int*>(&h);
}

__device__ __forceinline__ void gload_lds16(const void* g, void* l) {
    __builtin_amdgcn_global_load_lds(
        (__attribute__((address_space(1))) unsigned int*)g,
        (__attribute__((address_space(3))) unsigned int*)l, 16, 0, 0);
}

// LDS swizzle for [128 rows][64 bf16] regions (128 B/row): XOR chunk with row&7.
__device__ __forceinline__ int swz128(int by) {
    return by ^ (((by >> 7) & 7) << 4);
}

// ---------------------------------------------------------------- fused converts (1 launch)
__global__ void cvt_all_kernel(const float* __restrict__ x,  const float* __restrict__ wq,
                               const float* __restrict__ wk, const float* __restrict__ wv,
                               const float* __restrict__ wo,
                               unsigned short* __restrict__ xb,
                               unsigned short* __restrict__ wqkv,
                               unsigned short* __restrict__ wob) {
    const int i = blockIdx.x * 256 + threadIdx.x; // 0 .. 4718591 (float4 units)
    const float* src;
    unsigned short* dst;
    int off;
    if (i < 2097152)      { src = x;  dst = xb;   off = i; }
    else if (i < 3145728) { src = wq; dst = wqkv; off = i - 2097152; }
    else if (i < 3407872) { src = wk; dst = wqkv + (size_t)2048 * 2048; off = i - 3145728; }
    else if (i < 3670016) { src = wv; dst = wqkv + (size_t)2560 * 2048; off = i - 3407872; }
    else                  { src = wo; dst = wob;  off = i - 3670016; }
    const float4 v = ((const float4*)src)[off];
    uint2 o;
    o.x = pack_bf2(v.x, v.y);
    o.y = pack_bf2(v.z, v.w);
    ((uint2*)dst)[off] = o;
}

// ---------------------------------------------------------------- doc starts
__global__ void docstart_kernel(const int* __restrict__ sid, int* __restrict__ ds) {
    const int i = blockIdx.x * 256 + threadIdx.x; // 0..4095
    const int b = i >> 11, s = i & 2047;
    const int* row = sid + b * 2048;
    const int v = row[s];
    int lo = 0, hi = s;
    while (lo < hi) { const int mid = (lo + hi) >> 1; if (row[mid] < v) lo = mid + 1; else hi = mid; }
    ds[i] = lo;
}

// ---------------------------------------------------------------- QKV 256x256 8-phase GEMM (round-6/9 verified, FROZEN)
#define QKV_K 2048
#define QKV_NT 32
__global__ __launch_bounds__(512, 2) void gemm_qkv8(
    const unsigned short* __restrict__ A,
    const unsigned short* __restrict__ B,
    unsigned short* __restrict__ oq,
    unsigned short* __restrict__ ok,
    unsigned short* __restrict__ ov)
{
    __shared__ __align__(16) unsigned short S[2][2][2][8192]; // 128 KiB
    const int tid = threadIdx.x, lane = tid & 63, w = tid >> 6;
    const int wr = w >> 2, wc = w & 3;
    const int lr = lane & 15, lc = lane >> 4;

    // XCD swizzle over 192 blocks (192 % 8 == 0)
    int bid = blockIdx.x;
    bid = (bid & 7) * 24 + (bid >> 3);
    const int m0 = (bid / 12) * 256, n0 = (bid % 12) * 256;

    // staging geometry: linear LDS dest, inverse-swizzled global source (rule #21)
    const int o0 = (w << 11) + (lane << 4);
    const int o1 = o0 + 1024;
    const int v0 = swz128(o0), v1 = swz128(o1);
    const int r0 = v0 >> 7, c0 = (v0 & 127) >> 1;
    const int r1 = v1 >> 7, c1 = (v1 & 127) >> 1;
    const size_t aoff0 = (size_t)(m0 + r0) * QKV_K + c0;
    const size_t aoff1 = (size_t)(m0 + r1) * QKV_K + c1;
    const size_t boff0 = (size_t)(n0 + r0) * QKV_K + c0;
    const size_t boff1 = (size_t)(n0 + r1) * QKV_K + c1;
    const int d0 = o0 >> 1, d1 = o1 >> 1;

    f32x4 acc[2][2][4][2];
#pragma unroll
    for (int a = 0; a < 2; a++)
#pragma unroll
        for (int bq = 0; bq < 2; bq++)
#pragma unroll
            for (int i = 0; i < 4; i++)
#pragma unroll
                for (int j = 0; j < 2; j++) acc[a][bq][i][j] = (f32x4){0.f, 0.f, 0.f, 0.f};

    bf16x8 Af[4][2], Bf0[2][2], Bf1[2][2];

    auto STAGE_A = [&](int bf, int h, int kt) {
        gload_lds16(A + aoff0 + (size_t)h * 128 * QKV_K + (size_t)kt * 64, &S[bf][0][h][d0]);
        gload_lds16(A + aoff1 + (size_t)h * 128 * QKV_K + (size_t)kt * 64, &S[bf][0][h][d1]);
    };
    auto STAGE_B = [&](int bf, int h, int kt) {
        gload_lds16(B + boff0 + (size_t)h * 128 * QKV_K + (size_t)kt * 64, &S[bf][1][h][d0]);
        gload_lds16(B + boff1 + (size_t)h * 128 * QKV_K + (size_t)kt * 64, &S[bf][1][h][d1]);
    };
    auto LDA = [&](int bf, int mh) {
#pragma unroll
        for (int i = 0; i < 4; i++)
#pragma unroll
            for (int kh = 0; kh < 2; kh++) {
                const int by = swz128(((wr * 64 + i * 16 + lr) << 7) + (kh << 6) + (lc << 4));
                Af[i][kh] = *(const bf16x8*)((const char*)&S[bf][0][mh][0] + by);
            }
    };
    auto LDB = [&](int bf, int nh, bf16x8 (&Bf)[2][2]) {
#pragma unroll
        for (int j = 0; j < 2; j++)
#pragma unroll
            for (int kh = 0; kh < 2; kh++) {
                const int by = swz128(((wc * 32 + j * 16 + lr) << 7) + (kh << 6) + (lc << 4));
                Bf[j][kh] = *(const bf16x8*)((const char*)&S[bf][1][nh][0] + by);
            }
    };
    auto QUAD = [&](f32x4 (&ac)[4][2], bf16x8 (&Bf)[2][2]) {
        __builtin_amdgcn_s_setprio(1);
#pragma unroll
        for (int i = 0; i < 4; i++)
#pragma unroll
            for (int j = 0; j < 2; j++)
#pragma unroll
                for (int kh = 0; kh < 2; kh++)
                    ac[i][j] = MFMA16(Af[i][kh], Bf[j][kh], ac[i][j]);
        __builtin_amdgcn_s_setprio(0);
    };

#define BAR() __builtin_amdgcn_s_barrier()
#define LGKM0() asm volatile("s_waitcnt lgkmcnt(0)" ::: "memory")

    // ---- prologue: tile0 (A0,A1,B0,B1)->buf0; A0[1],B1[1],A1[1]->buf1; drain to 3
    STAGE_A(0, 0, 0); STAGE_A(0, 1, 0); STAGE_B(0, 0, 0); STAGE_B(0, 1, 0);
    STAGE_A(1, 0, 1); STAGE_B(1, 1, 1); STAGE_A(1, 1, 1);
    asm volatile("s_waitcnt vmcnt(6)" ::: "memory");
    BAR();

    auto GROUP = [&](int g, int bf) {
        // ph1: quadrant (0,0); stage B0[g+1] -> other buf
        LDA(bf, 0); LDB(bf, 0, Bf0);
        if (g + 1 < QKV_NT) STAGE_B(bf ^ 1, 0, g + 1);
        BAR(); LGKM0();
        QUAD(acc[0][0], Bf0);
        BAR();
        // ph2: (0,1); stage A0[g+2] -> current buf
        LDB(bf, 1, Bf1);
        if (g + 2 < QKV_NT) STAGE_A(bf, 0, g + 2);
        BAR(); LGKM0();
        QUAD(acc[0][1], Bf1);
        BAR();
        // ph3: (1,1); stage B1[g+2] -> current buf
        LDA(bf, 1);
        if (g + 2 < QKV_NT) STAGE_B(bf, 1, g + 2);
        BAR(); LGKM0();
        QUAD(acc[1][1], Bf1);
        BAR();
        // ph4: (1,0); stage A1[g+2] -> current buf
        if (g + 2 < QKV_NT) STAGE_A(bf, 1, g + 2);
        BAR();
        QUAD(acc[1][0], Bf0);
        if (g == QKV_NT - 2) { asm volatile("s_waitcnt vmcnt(0)" ::: "memory"); }
        else                 { asm volatile("s_waitcnt vmcnt(6)" ::: "memory"); }
        BAR();
    };

#pragma unroll 1
    for (int g = 0; g < QKV_NT; g += 2) {
        GROUP(g, 0);
        GROUP(g + 1, 1);
    }

    // ---- epilogue: scatter into Q:(B,32,S,64), K/V:(B,8,S,64) bf16
#pragma unroll
    for (int mh = 0; mh < 2; mh++)
#pragma unroll
        for (int nh = 0; nh < 2; nh++)
#pragma unroll
            for (int i = 0; i < 4; i++)
#pragma unroll
                for (int j = 0; j < 2; j++) {
                    const int n = n0 + nh * 128 + wc * 32 + j * 16 + lr;
                    const int d = n & 63;
                    const int hh6 = n >> 6;
#pragma unroll
                    for (int r = 0; r < 4; r++) {
                        const int m = m0 + mh * 128 + wr * 64 + i * 16 + lc * 4 + r;
                        const int bb = m >> 11, s = m & 2047;
                        const unsigned short val = f2bf(acc[mh][nh][i][j][r]);
                        if (n < 2048) {
                            oq[((((size_t)bb * 32 + hh6) * 2048 + s) << 6) + d] = val;
                        } else if (n < 2560) {
                            ok[((((size_t)bb * 8 + (hh6 - 32)) * 2048 + s) << 6) + d] = val;
                        } else {
                            ov[((((size_t)bb * 8 + (hh6 - 40)) * 2048 + s) << 6) + d] = val;
                        }
                    }
                }
}
#undef BAR
#undef LGKM0

// ---------------------------------------------------------------- RoPE, vectorized 4 pairs/thread
__global__ void rope_kernel(unsigned short* __restrict__ Qb,
                            unsigned short* __restrict__ Kb,
                            const float* __restrict__ fc)
{
    const int NQ = 64 * 2048 * 8; // Q thread count (2*32 heads)
    int j = blockIdx.x * 256 + threadIdx.x;
    unsigned short* base;
    if (j < NQ) base = Qb;
    else { base = Kb; j -= NQ; }
    const int g = j & 7, s = (j >> 3) & 2047, bh = j >> 14;
    const size_t off = (((size_t)bh * 2048 + s) << 6) + g * 8;
    uint4 u = *(uint4*)&base[off];
    const float4 cs0 = *(const float4*)&fc[((s << 5) + g * 4) << 1];       // c0 s0 c1 s1
    const float4 cs1 = *(const float4*)&fc[(((s << 5) + g * 4) << 1) + 4]; // c2 s2 c3 s3
    unsigned int* uw = (unsigned int*)&u;
    float c[4] = {cs0.x, cs0.z, cs1.x, cs1.z};
    float sn[4] = {cs0.y, cs0.w, cs1.y, cs1.w};
#pragma unroll
    for (int q = 0; q < 4; q++) {
        const float t0 = bf2f((unsigned short)(uw[q] & 0xffffu));
        const float t1 = bf2f((unsigned short)(uw[q] >> 16));
        uw[q] = pack_bf2(fmaf(t0, c[q], -t1 * sn[q]), fmaf(t0, sn[q], t1 * c[q]));
    }
    *(uint4*)&base[off] = u;
}

// ---------------------------------------------------------------- bt-GEMM (m97) for out-proj + chunk-XOR LDS swizzle (no setprio)
template <int EPI>
__global__ __launch_bounds__(256) void gemm_bt(
    const unsigned short* __restrict__ A,
    const unsigned short* __restrict__ B,
    int K, int N,
    unsigned short* __restrict__ oq,
    unsigned short* __restrict__ ok,
    unsigned short* __restrict__ ov,
    float* __restrict__ of)
{
    __shared__ __align__(16) unsigned short sA[128 * 32];
    __shared__ __align__(16) unsigned short sB[128 * 32];
    const int tid = threadIdx.x;
    const int lane = tid & 63, wave = tid >> 6;
    const int wr = wave >> 1, wc = wave & 1;
    const int lr = lane & 15, lc = lane >> 4;

    int bid = blockIdx.y * gridDim.x + blockIdx.x;
    const int cpx = (gridDim.x * gridDim.y) >> 3;
    bid = (bid & 7) * cpx + (bid >> 3);
    const int m0 = (bid / gridDim.x) * 128, n0 = (bid % gridDim.x) * 128;

    f32x4 acc[4][4];
#pragma unroll
    for (int i = 0; i < 4; i++)
#pragma unroll
        for (int j = 0; j < 4; j++) acc[i][j] = (f32x4){0.f, 0.f, 0.f, 0.f};

    const int u0 = tid, u1 = tid + 256;
    const int su0 = (u0 & 3) ^ ((u0 >> 3) & 3); // inverse-swizzled source chunk
    const int su1 = (u1 & 3) ^ ((u1 >> 3) & 3);
    const int cX = (lc ^ ((lr >> 1) & 3)) * 8;  // swizzled read chunk (elements)
    for (int k0 = 0; k0 < K; k0 += 32) {
        __syncthreads();
        gload_lds16(A + (size_t)(m0 + (u0 >> 2)) * K + k0 + su0 * 8, &sA[u0 * 8]);
        gload_lds16(A + (size_t)(m0 + (u1 >> 2)) * K + k0 + su1 * 8, &sA[u1 * 8]);
        gload_lds16(B + (size_t)(n0 + (u0 >> 2)) * K + k0 + su0 * 8, &sB[u0 * 8]);
        gload_lds16(B + (size_t)(n0 + (u1 >> 2)) * K + k0 + su1 * 8, &sB[u1 * 8]);
        __syncthreads();
        bf16x8 af[4], bfv[4];
#pragma unroll
        for (int i = 0; i < 4; i++) {
            af[i]  = *(const bf16x8*)&sA[(wr * 64 + i * 16 + lr) * 32 + cX];
            bfv[i] = *(const bf16x8*)&sB[(wc * 64 + i * 16 + lr) * 32 + cX];
        }
#pragma unroll
        for (int i = 0; i < 4; i++)
#pragma unroll
            for (int j = 0; j < 4; j++) acc[i][j] = MFMA16(af[i], bfv[j], acc[i][j]);
    }

    if (EPI == 0) {
#pragma unroll
        for (int i = 0; i < 4; i++) {
#pragma unroll
            for (int j = 0; j < 4; j++) {
                const int n = n0 + wc * 64 + j * 16 + lr;
                const int d = n & 63;
#pragma unroll
                for (int r = 0; r < 4; r++) {
                    const int m = m0 + wr * 64 + i * 16 + lc * 4 + r;
                    const int bb = m >> 11, s = m & 2047;
                    const unsigned short val = f2bf(acc[i][j][r]);
                    if (n < 2048) {
                        const int hh = n >> 6;
                        oq[((((size_t)bb * 32 + hh) * 2048 + s) << 6) + d] = val;
                    } else if (n < 2560) {
                        const int hh = (n >> 6) - 32;
                        ok[((((size_t)bb * 8 + hh) * 2048 + s) << 6) + d] = val;
                    } else {
                        const int hh = (n >> 6) - 40;
                        ov[((((size_t)bb * 8 + hh) * 2048 + s) << 6) + d] = val;
                    }
                }
            }
        }
    } else {
#pragma unroll
        for (int i = 0; i < 4; i++)
#pragma unroll
            for (int j = 0; j < 4; j++)
#pragma unroll
                for (int r = 0; r < 4; r++) {
                    const int m = m0 + wr * 64 + i * 16 + lc * 4 + r;
                    const int n = n0 + wc * 64 + j * 16 + lr;
                    of[(size_t)m * N + n] = acc[i][j][r];
                }
    }
}

// ---------------------------------------------------------------- flash attention v7: QBLK=128 + exp2 + defer-max (no setprio)
__global__ __launch_bounds__(512) void attn_kernel(
    const unsigned short* __restrict__ Q,
    const unsigned short* __restrict__ K,
    const unsigned short* __restrict__ V,
    const int* __restrict__ dstart,
    unsigned short* __restrict__ AO)
{
    const int qt = 15 - blockIdx.x; // heavy blocks first
    const int h = blockIdx.y, b = blockIdx.z;
    const int kvh = h >> 2;
    const int tid = threadIdx.x, lane = tid & 63, wave = tid >> 6;
    const int lr = lane & 15, lc = lane >> 4;
    const int q0 = qt * 128;
    const int qw = q0 + wave * 16;

    __shared__ __align__(16) unsigned short sK[2][64 * 64];   // chunk-XOR swizzled
    __shared__ __align__(16) unsigned short sVt[2][64][72];   // V^T; flat [128][72] in epilogue

    const unsigned short* Qh = Q + (((size_t)b * 32 + h) * 2048) * 64;
    const unsigned short* Kh = K + (((size_t)b * 8 + kvh) * 2048) * 64;
    const unsigned short* Vh = V + (((size_t)b * 8 + kvh) * 2048) * 64;

    const bf16x8 qf0 = *(const bf16x8*)&Qh[(size_t)(qw + lr) * 64 + lc * 8];
    const bf16x8 qf1 = *(const bf16x8*)&Qh[(size_t)(qw + lr) * 64 + 32 + lc * 8];

    const int qglob = qw + lr;
    const int dsl = dstart[b * 2048 + qglob];
    const int ds_wmin = dstart[b * 2048 + qw];
    const int t0 = dstart[b * 2048 + q0] & ~63;

    const int w8 = wave * 8;
    const int kr = tid >> 3, kc = tid & 7; // 512 threads cover the 64x64 K tile

    auto STAGE_K = [&](int t, int c) {
        gload_lds16(Kh + (size_t)(t + kr) * 64 + ((kc ^ (kr & 7)) * 8), &sK[c][tid * 8]);
    };
    auto WRITE_V = [&](const uint4& va, int c) {
        const unsigned short* pa = (const unsigned short*)&va;
#pragma unroll
        for (int e = 0; e < 8; e++) sVt[c][w8 + e][lane] = pa[e];
    };

    // softmax in exp2 domain: S_scaled = S * 0.125 * log2(e)
    const float SC2 = 0.125f * 1.4426950408889634f;

    float mrow = -1e30f, lrow = 0.f;
    f32x4 oacc[4];
#pragma unroll
    for (int j = 0; j < 4; j++) oacc[j] = (f32x4){0.f, 0.f, 0.f, 0.f};

    // ---- prologue: stage tile t0 into buf 0
    STAGE_K(t0, 0);
    {
        const uint4 va = *(const uint4*)&Vh[(size_t)(t0 + lane) * 64 + w8];
        asm volatile("s_waitcnt vmcnt(0)" ::: "memory");
        WRITE_V(va, 0);
    }
    __syncthreads();

    int cb = 0;
    for (int t = t0; t < q0 + 128; t += 64, cb ^= 1) {
        const bool more = (t < q0 + 64); // block-uniform
        uint4 va;
        if (more) {
            STAGE_K(t + 64, cb ^ 1);
            va = *(const uint4*)&Vh[(size_t)(t + 64 + lane) * 64 + w8];
        }
        const bool act = !(t > qw + 15 || t + 63 < ds_wmin); // wave-uniform
        union { unsigned int w[4]; bf16x8 v; } B0, B1;

        if (act) {
            // --- QK^T swapped: C[k][q], k = kk*16 + lc*4 + r, q = qw + lr
            f32x4 sc[4];
#pragma unroll
            for (int kk = 0; kk < 4; kk++) {
                const int krow = kk * 16 + lr;
                const bf16x8 kf0 = *(const bf16x8*)&sK[cb][krow * 64 + ((lc ^ (lr & 7)) * 8)];
                const bf16x8 kf1 = *(const bf16x8*)&sK[cb][krow * 64 + (((4 + lc) ^ (lr & 7)) * 8)];
                f32x4 a = (f32x4){0.f, 0.f, 0.f, 0.f};
                a = MFMA16(kf0, qf0, a);
                a = MFMA16(kf1, qf1, a);
                sc[kk] = a;
            }
            // --- mask + scale (exp2 domain) + in-lane softmax
            float vmax = -3e38f;
#pragma unroll
            for (int kk = 0; kk < 4; kk++)
#pragma unroll
                for (int r = 0; r < 4; r++) {
                    const int kpos = t + kk * 16 + lc * 4 + r;
                    const bool okm = (kpos <= qglob) && (kpos >= dsl);
                    sc[kk][r] = okm ? sc[kk][r] * SC2 : -3e38f;
                    vmax = fmaxf(vmax, sc[kk][r]);
                }
            vmax = fmaxf(vmax, __shfl_xor(vmax, 16));
            vmax = fmaxf(vmax, __shfl_xor(vmax, 32));
            // T13 defer-max: skip O/l rescale while vmax <= mrow + 8 (P bounded by 2^8)
            if (!__all(vmax <= mrow + 8.f)) {
                const float mnew = fmaxf(mrow, vmax);
                const float corr = __builtin_exp2f(mrow - mnew);
                mrow = mnew;
                lrow *= corr;
#pragma unroll
                for (int j = 0; j < 4; j++)
#pragma unroll
                    for (int r = 0; r < 4; r++) oacc[j][r] *= corr;
            }

            float rsum = 0.f;
            unsigned int pk[4][2];
#pragma unroll
            for (int kk = 0; kk < 4; kk++) {
                const float p0 = __builtin_exp2f(sc[kk][0] - mrow);
                const float p1 = __builtin_exp2f(sc[kk][1] - mrow);
                const float p2 = __builtin_exp2f(sc[kk][2] - mrow);
                const float p3 = __builtin_exp2f(sc[kk][3] - mrow);
                rsum += (p0 + p1) + (p2 + p3);
                pk[kk][0] = pack_bf2(p0, p1);
                pk[kk][1] = pack_bf2(p2, p3);
            }
            rsum += __shfl_xor(rsum, 16);
            rsum += __shfl_xor(rsum, 32);
            lrow += rsum;

            // --- redistribute P -> PV B-frags (shuffle both kk candidates, select by dest lc>>1)
            const int srcEven = 32 * (lc & 1) + lr;
            const int srcOdd  = srcEven + 16;
            const bool hiKK = (lc & 2) != 0;
            unsigned int a, c;
            a = __shfl(pk[0][0], srcEven); c = __shfl(pk[1][0], srcEven); B0.w[0] = hiKK ? c : a;
            a = __shfl(pk[0][1], srcEven); c = __shfl(pk[1][1], srcEven); B0.w[1] = hiKK ? c : a;
            a = __shfl(pk[0][0], srcOdd);  c = __shfl(pk[1][0], srcOdd);  B0.w[2] = hiKK ? c : a;
            a = __shfl(pk[0][1], srcOdd);  c = __shfl(pk[1][1], srcOdd);  B0.w[3] = hiKK ? c : a;
            a = __shfl(pk[2][0], srcEven); c = __shfl(pk[3][0], srcEven); B1.w[0] = hiKK ? c : a;
            a = __shfl(pk[2][1], srcEven); c = __shfl(pk[3][1], srcEven); B1.w[1] = hiKK ? c : a;
            a = __shfl(pk[2][0], srcOdd);  c = __shfl(pk[3][0], srcOdd);  B1.w[2] = hiKK ? c : a;
            a = __shfl(pk[2][1], srcOdd);  c = __shfl(pk[3][1], srcOdd);  B1.w[3] = hiKK ? c : a;
        }

        if (more) {
            asm volatile("s_waitcnt vmcnt(0)" ::: "memory"); // V(t+64) regs + K(t+64) LDS landed
            WRITE_V(va, cb ^ 1);
        }

        if (act) {
            // --- PV: O^T = V^T x P^T, C[d][q]: d = j*16 + lc*4 + r, q = qw + lr
#pragma unroll
            for (int j = 0; j < 4; j++) {
                const bf16x8 a0 = *(const bf16x8*)&sVt[cb][j * 16 + lr][lc * 8];
                const bf16x8 a1 = *(const bf16x8*)&sVt[cb][j * 16 + lr][32 + lc * 8];
                oacc[j] = MFMA16(a0, B0.v, oacc[j]);
                oacc[j] = MFMA16(a1, B1.v, oacc[j]);
            }
        }
        __syncthreads();
    }

    // --- epilogue: transpose via LDS (sVt viewed as flat [128][72]), coalesced stores
    unsigned short (*E)[72] = (unsigned short (*)[72])&sVt[0][0][0];
    const float inv = 1.0f / lrow;
#pragma unroll
    for (int j = 0; j < 4; j++)
#pragma unroll
        for (int p = 0; p < 2; p++) {
            const unsigned int w = pack_bf2(oacc[j][2 * p] * inv, oacc[j][2 * p + 1] * inv);
            *(unsigned int*)&E[wave * 16 + lr][j * 16 + lc * 4 + 2 * p] = w;
        }
    __syncthreads();
#pragma unroll
    for (int half = 0; half < 2; half++) {
        const int c = lane + 64 * half;
        const int row = c >> 3, ch = c & 7;
        const uint4 o = *(const uint4*)&E[wave * 16 + row][ch * 8];
        *(uint4*)&AO[((size_t)b * 2048 + qw + row) * 2048 + h * 64 + ch * 8] = o;
    }
}

// ---------------------------------------------------------------- host
extern "C" void kernel_launch(void* const* d_in, const int* in_sizes, int n_in,
                              void* d_out, int out_size, void* d_ws, size_t ws_size,
                              hipStream_t stream) {
    const float* x  = (const float*)d_in[0];
    const float* fc = (const float*)d_in[1];
    const int* sid  = (const int*)d_in[2];
    const float* wq = (const float*)d_in[3];
    const float* wk = (const float*)d_in[4];
    const float* wv = (const float*)d_in[5];
    const float* wo = (const float*)d_in[6];
    float* out = (float*)d_out;

    unsigned short* xb   = (unsigned short*)d_ws;
    unsigned short* wqkv = xb + (size_t)4096 * 2048;
    unsigned short* wob  = wqkv + (size_t)3072 * 2048;
    unsigned short* Qb   = wob + (size_t)2048 * 2048;
    unsigned short* Kb   = Qb + (size_t)2 * 32 * 2048 * 64;
    unsigned short* Vb   = Kb + (size_t)2 * 8 * 2048 * 64;
    unsigned short* AO   = Vb + (size_t)2 * 8 * 2048 * 64;
    int* dstart = (int*)(AO + (size_t)4096 * 2048);

    cvt_all_kernel<<<18432, 256, 0, stream>>>(x, wq, wk, wv, wo, xb, wqkv, wob);
    docstart_kernel<<<16, 256, 0, stream>>>(sid, dstart);
    gemm_qkv8<<<dim3(192), 512, 0, stream>>>(xb, wqkv, Qb, Kb, Vb);
    rope_kernel<<<5120, 256, 0, stream>>>(Qb, Kb, fc);
    attn_kernel<<<dim3(16, 32, 2), 512, 0, stream>>>(Qb, Kb, Vb, dstart, AO);
    gemm_bt<1><<<dim3(16, 32), 256, 0, stream>>>(AO, wob, 2048, 2048, nullptr, nullptr, nullptr, out);
}

// Round 14
// 192.551 us; speedup vs baseline: 1.0368x; 1.0267x over previous
//
#include <hip/hip_runtime.h>
#include <hip/hip_bf16.h>

typedef __attribute__((ext_vector_type(8))) short bf16x8;
typedef __attribute__((ext_vector_type(4))) float f32x4;

#define MFMA16(A, B, C) __builtin_amdgcn_mfma_f32_16x16x32_bf16(A, B, C, 0, 0, 0)

__device__ __forceinline__ unsigned short f2bf(float f) {
    unsigned int u = __float_as_uint(f);
    u += 0x7fffu + ((u >> 16) & 1u);
    return (unsigned short)(u >> 16);
}
__device__ __forceinline__ float bf2f(unsigned short h) {
    return __uint_as_float(((unsigned int)h) << 16);
}
__device__ __forceinline__ unsigned int pack_bf2(float lo, float hi) {
    __hip_bfloat162 h = __float22bfloat162_rn(make_float2(lo, hi)); // v_cvt_pk_bf16_f32
    return *reinterpret_cast<unsigned int*>(&h);
}

__device__ __forceinline__ void gload_lds16(const void* g, void* l) {
    __builtin_amdgcn_global_load_lds(
        (__attribute__((address_space(1))) unsigned int*)g,
        (__attribute__((address_space(3))) unsigned int*)l, 16, 0, 0);
}

// LDS swizzle for [128 rows][64 bf16] regions (128 B/row): XOR chunk with row&7.
__device__ __forceinline__ int swz128(int by) {
    return by ^ (((by >> 7) & 7) << 4);
}

// ---------------------------------------------------------------- fused converts (1 launch)
__global__ void cvt_all_kernel(const float* __restrict__ x,  const float* __restrict__ wq,
                               const float* __restrict__ wk, const float* __restrict__ wv,
                               const float* __restrict__ wo,
                               unsigned short* __restrict__ xb,
                               unsigned short* __restrict__ wqkv,
                               unsigned short* __restrict__ wob) {
    const int i = blockIdx.x * 256 + threadIdx.x; // 0 .. 4718591 (float4 units)
    const float* src;
    unsigned short* dst;
    int off;
    if (i < 2097152)      { src = x;  dst = xb;   off = i; }
    else if (i < 3145728) { src = wq; dst = wqkv; off = i - 2097152; }
    else if (i < 3407872) { src = wk; dst = wqkv + (size_t)2048 * 2048; off = i - 3145728; }
    else if (i < 3670016) { src = wv; dst = wqkv + (size_t)2560 * 2048; off = i - 3407872; }
    else                  { src = wo; dst = wob;  off = i - 3670016; }
    const float4 v = ((const float4*)src)[off];
    uint2 o;
    o.x = pack_bf2(v.x, v.y);
    o.y = pack_bf2(v.z, v.w);
    ((uint2*)dst)[off] = o;
}

// ---------------------------------------------------------------- doc starts
__global__ void docstart_kernel(const int* __restrict__ sid, int* __restrict__ ds) {
    const int i = blockIdx.x * 256 + threadIdx.x; // 0..4095
    const int b = i >> 11, s = i & 2047;
    const int* row = sid + b * 2048;
    const int v = row[s];
    int lo = 0, hi = s;
    while (lo < hi) { const int mid = (lo + hi) >> 1; if (row[mid] < v) lo = mid + 1; else hi = mid; }
    ds[i] = lo;
}

// ---------------------------------------------------------------- QKV 256x256 8-phase GEMM (round-6/9 verified, FROZEN)
#define QKV_K 2048
#define QKV_NT 32
__global__ __launch_bounds__(512, 2) void gemm_qkv8(
    const unsigned short* __restrict__ A,
    const unsigned short* __restrict__ B,
    unsigned short* __restrict__ oq,
    unsigned short* __restrict__ ok,
    unsigned short* __restrict__ ov)
{
    __shared__ __align__(16) unsigned short S[2][2][2][8192]; // 128 KiB
    const int tid = threadIdx.x, lane = tid & 63, w = tid >> 6;
    const int wr = w >> 2, wc = w & 3;
    const int lr = lane & 15, lc = lane >> 4;

    // XCD swizzle over 192 blocks (192 % 8 == 0)
    int bid = blockIdx.x;
    bid = (bid & 7) * 24 + (bid >> 3);
    const int m0 = (bid / 12) * 256, n0 = (bid % 12) * 256;

    // staging geometry: linear LDS dest, inverse-swizzled global source (rule #21)
    const int o0 = (w << 11) + (lane << 4);
    const int o1 = o0 + 1024;
    const int v0 = swz128(o0), v1 = swz128(o1);
    const int r0 = v0 >> 7, c0 = (v0 & 127) >> 1;
    const int r1 = v1 >> 7, c1 = (v1 & 127) >> 1;
    const size_t aoff0 = (size_t)(m0 + r0) * QKV_K + c0;
    const size_t aoff1 = (size_t)(m0 + r1) * QKV_K + c1;
    const size_t boff0 = (size_t)(n0 + r0) * QKV_K + c0;
    const size_t boff1 = (size_t)(n0 + r1) * QKV_K + c1;
    const int d0 = o0 >> 1, d1 = o1 >> 1;

    f32x4 acc[2][2][4][2];
#pragma unroll
    for (int a = 0; a < 2; a++)
#pragma unroll
        for (int bq = 0; bq < 2; bq++)
#pragma unroll
            for (int i = 0; i < 4; i++)
#pragma unroll
                for (int j = 0; j < 2; j++) acc[a][bq][i][j] = (f32x4){0.f, 0.f, 0.f, 0.f};

    bf16x8 Af[4][2], Bf0[2][2], Bf1[2][2];

    auto STAGE_A = [&](int bf, int h, int kt) {
        gload_lds16(A + aoff0 + (size_t)h * 128 * QKV_K + (size_t)kt * 64, &S[bf][0][h][d0]);
        gload_lds16(A + aoff1 + (size_t)h * 128 * QKV_K + (size_t)kt * 64, &S[bf][0][h][d1]);
    };
    auto STAGE_B = [&](int bf, int h, int kt) {
        gload_lds16(B + boff0 + (size_t)h * 128 * QKV_K + (size_t)kt * 64, &S[bf][1][h][d0]);
        gload_lds16(B + boff1 + (size_t)h * 128 * QKV_K + (size_t)kt * 64, &S[bf][1][h][d1]);
    };
    auto LDA = [&](int bf, int mh) {
#pragma unroll
        for (int i = 0; i < 4; i++)
#pragma unroll
            for (int kh = 0; kh < 2; kh++) {
                const int by = swz128(((wr * 64 + i * 16 + lr) << 7) + (kh << 6) + (lc << 4));
                Af[i][kh] = *(const bf16x8*)((const char*)&S[bf][0][mh][0] + by);
            }
    };
    auto LDB = [&](int bf, int nh, bf16x8 (&Bf)[2][2]) {
#pragma unroll
        for (int j = 0; j < 2; j++)
#pragma unroll
            for (int kh = 0; kh < 2; kh++) {
                const int by = swz128(((wc * 32 + j * 16 + lr) << 7) + (kh << 6) + (lc << 4));
                Bf[j][kh] = *(const bf16x8*)((const char*)&S[bf][1][nh][0] + by);
            }
    };
    auto QUAD = [&](f32x4 (&ac)[4][2], bf16x8 (&Bf)[2][2]) {
        __builtin_amdgcn_s_setprio(1);
#pragma unroll
        for (int i = 0; i < 4; i++)
#pragma unroll
            for (int j = 0; j < 2; j++)
#pragma unroll
                for (int kh = 0; kh < 2; kh++)
                    ac[i][j] = MFMA16(Af[i][kh], Bf[j][kh], ac[i][j]);
        __builtin_amdgcn_s_setprio(0);
    };

#define BAR() __builtin_amdgcn_s_barrier()
#define LGKM0() asm volatile("s_waitcnt lgkmcnt(0)" ::: "memory")

    // ---- prologue: tile0 (A0,A1,B0,B1)->buf0; A0[1],B1[1],A1[1]->buf1; drain to 3
    STAGE_A(0, 0, 0); STAGE_A(0, 1, 0); STAGE_B(0, 0, 0); STAGE_B(0, 1, 0);
    STAGE_A(1, 0, 1); STAGE_B(1, 1, 1); STAGE_A(1, 1, 1);
    asm volatile("s_waitcnt vmcnt(6)" ::: "memory");
    BAR();

    auto GROUP = [&](int g, int bf) {
        // ph1: quadrant (0,0); stage B0[g+1] -> other buf
        LDA(bf, 0); LDB(bf, 0, Bf0);
        if (g + 1 < QKV_NT) STAGE_B(bf ^ 1, 0, g + 1);
        BAR(); LGKM0();
        QUAD(acc[0][0], Bf0);
        BAR();
        // ph2: (0,1); stage A0[g+2] -> current buf
        LDB(bf, 1, Bf1);
        if (g + 2 < QKV_NT) STAGE_A(bf, 0, g + 2);
        BAR(); LGKM0();
        QUAD(acc[0][1], Bf1);
        BAR();
        // ph3: (1,1); stage B1[g+2] -> current buf
        LDA(bf, 1);
        if (g + 2 < QKV_NT) STAGE_B(bf, 1, g + 2);
        BAR(); LGKM0();
        QUAD(acc[1][1], Bf1);
        BAR();
        // ph4: (1,0); stage A1[g+2] -> current buf
        if (g + 2 < QKV_NT) STAGE_A(bf, 1, g + 2);
        BAR();
        QUAD(acc[1][0], Bf0);
        if (g == QKV_NT - 2) { asm volatile("s_waitcnt vmcnt(0)" ::: "memory"); }
        else                 { asm volatile("s_waitcnt vmcnt(6)" ::: "memory"); }
        BAR();
    };

#pragma unroll 1
    for (int g = 0; g < QKV_NT; g += 2) {
        GROUP(g, 0);
        GROUP(g + 1, 1);
    }

    // ---- epilogue: scatter into Q:(B,32,S,64), K/V:(B,8,S,64) bf16
#pragma unroll
    for (int mh = 0; mh < 2; mh++)
#pragma unroll
        for (int nh = 0; nh < 2; nh++)
#pragma unroll
            for (int i = 0; i < 4; i++)
#pragma unroll
                for (int j = 0; j < 2; j++) {
                    const int n = n0 + nh * 128 + wc * 32 + j * 16 + lr;
                    const int d = n & 63;
                    const int hh6 = n >> 6;
#pragma unroll
                    for (int r = 0; r < 4; r++) {
                        const int m = m0 + mh * 128 + wr * 64 + i * 16 + lc * 4 + r;
                        const int bb = m >> 11, s = m & 2047;
                        const unsigned short val = f2bf(acc[mh][nh][i][j][r]);
                        if (n < 2048) {
                            oq[((((size_t)bb * 32 + hh6) * 2048 + s) << 6) + d] = val;
                        } else if (n < 2560) {
                            ok[((((size_t)bb * 8 + (hh6 - 32)) * 2048 + s) << 6) + d] = val;
                        } else {
                            ov[((((size_t)bb * 8 + (hh6 - 40)) * 2048 + s) << 6) + d] = val;
                        }
                    }
                }
}
#undef BAR
#undef LGKM0

// ---------------------------------------------------------------- RoPE on K only (Q fused into attn), 4 pairs/thread
__global__ void rope_k_kernel(unsigned short* __restrict__ Kb,
                              const float* __restrict__ fc)
{
    const int j = blockIdx.x * 256 + threadIdx.x; // 0 .. 262143
    const int g = j & 7, s = (j >> 3) & 2047, bh = j >> 14; // bh in 0..15
    const size_t off = (((size_t)bh * 2048 + s) << 6) + g * 8;
    uint4 u = *(uint4*)&Kb[off];
    const float4 cs0 = *(const float4*)&fc[((s << 5) + g * 4) << 1];       // c0 s0 c1 s1
    const float4 cs1 = *(const float4*)&fc[(((s << 5) + g * 4) << 1) + 4]; // c2 s2 c3 s3
    unsigned int* uw = (unsigned int*)&u;
    float c[4] = {cs0.x, cs0.z, cs1.x, cs1.z};
    float sn[4] = {cs0.y, cs0.w, cs1.y, cs1.w};
#pragma unroll
    for (int q = 0; q < 4; q++) {
        const float t0 = bf2f((unsigned short)(uw[q] & 0xffffu));
        const float t1 = bf2f((unsigned short)(uw[q] >> 16));
        uw[q] = pack_bf2(fmaf(t0, c[q], -t1 * sn[q]), fmaf(t0, sn[q], t1 * c[q]));
    }
    *(uint4*)&Kb[off] = u;
}

// ---------------------------------------------------------------- bt-GEMM (m97, round-10 verified) for out-proj
template <int EPI>
__global__ __launch_bounds__(256) void gemm_bt(
    const unsigned short* __restrict__ A,
    const unsigned short* __restrict__ B,
    int K, int N,
    unsigned short* __restrict__ oq,
    unsigned short* __restrict__ ok,
    unsigned short* __restrict__ ov,
    float* __restrict__ of)
{
    __shared__ __align__(16) unsigned short sA[128 * 32];
    __shared__ __align__(16) unsigned short sB[128 * 32];
    const int tid = threadIdx.x;
    const int lane = tid & 63, wave = tid >> 6;
    const int wr = wave >> 1, wc = wave & 1;
    const int lr = lane & 15, lc = lane >> 4;

    int bid = blockIdx.y * gridDim.x + blockIdx.x;
    const int cpx = (gridDim.x * gridDim.y) >> 3;
    bid = (bid & 7) * cpx + (bid >> 3);
    const int m0 = (bid / gridDim.x) * 128, n0 = (bid % gridDim.x) * 128;

    f32x4 acc[4][4];
#pragma unroll
    for (int i = 0; i < 4; i++)
#pragma unroll
        for (int j = 0; j < 4; j++) acc[i][j] = (f32x4){0.f, 0.f, 0.f, 0.f};

    const int u0 = tid, u1 = tid + 256;
    for (int k0 = 0; k0 < K; k0 += 32) {
        __syncthreads();
        gload_lds16(A + (size_t)(m0 + (u0 >> 2)) * K + k0 + (u0 & 3) * 8, &sA[u0 * 8]);
        gload_lds16(A + (size_t)(m0 + (u1 >> 2)) * K + k0 + (u1 & 3) * 8, &sA[u1 * 8]);
        gload_lds16(B + (size_t)(n0 + (u0 >> 2)) * K + k0 + (u0 & 3) * 8, &sB[u0 * 8]);
        gload_lds16(B + (size_t)(n0 + (u1 >> 2)) * K + k0 + (u1 & 3) * 8, &sB[u1 * 8]);
        __syncthreads();
        bf16x8 af[4], bfv[4];
#pragma unroll
        for (int i = 0; i < 4; i++) {
            af[i]  = *(const bf16x8*)&sA[(wr * 64 + i * 16 + lr) * 32 + lc * 8];
            bfv[i] = *(const bf16x8*)&sB[(wc * 64 + i * 16 + lr) * 32 + lc * 8];
        }
#pragma unroll
        for (int i = 0; i < 4; i++)
#pragma unroll
            for (int j = 0; j < 4; j++) acc[i][j] = MFMA16(af[i], bfv[j], acc[i][j]);
    }

    if (EPI == 0) {
#pragma unroll
        for (int i = 0; i < 4; i++) {
#pragma unroll
            for (int j = 0; j < 4; j++) {
                const int n = n0 + wc * 64 + j * 16 + lr;
                const int d = n & 63;
#pragma unroll
                for (int r = 0; r < 4; r++) {
                    const int m = m0 + wr * 64 + i * 16 + lc * 4 + r;
                    const int bb = m >> 11, s = m & 2047;
                    const unsigned short val = f2bf(acc[i][j][r]);
                    if (n < 2048) {
                        const int hh = n >> 6;
                        oq[((((size_t)bb * 32 + hh) * 2048 + s) << 6) + d] = val;
                    } else if (n < 2560) {
                        const int hh = (n >> 6) - 32;
                        ok[((((size_t)bb * 8 + hh) * 2048 + s) << 6) + d] = val;
                    } else {
                        const int hh = (n >> 6) - 40;
                        ov[((((size_t)bb * 8 + hh) * 2048 + s) << 6) + d] = val;
                    }
                }
            }
        }
    } else {
#pragma unroll
        for (int i = 0; i < 4; i++)
#pragma unroll
            for (int j = 0; j < 4; j++)
#pragma unroll
                for (int r = 0; r < 4; r++) {
                    const int m = m0 + wr * 64 + i * 16 + lc * 4 + r;
                    const int n = n0 + wc * 64 + j * 16 + lr;
                    of[(size_t)m * N + n] = acc[i][j][r];
                }
    }
}

// ---------------------------------------------------------------- flash attention v8: round-10 v5 + fused Q-RoPE
// Q-rope is in-register at load: pairs (d, d^1) are adjacent within each lane's
// 8-elem chunk; 4 float4 fc loads + 16 FMA once per block, hidden under prologue.
__global__ __launch_bounds__(512) void attn_kernel(
    const unsigned short* __restrict__ Q,
    const unsigned short* __restrict__ K,
    const unsigned short* __restrict__ V,
    const int* __restrict__ dstart,
    const float* __restrict__ fc,
    unsigned short* __restrict__ AO)
{
    const int qt = 15 - blockIdx.x; // heavy blocks first
    const int h = blockIdx.y, b = blockIdx.z;
    const int kvh = h >> 2;
    const int tid = threadIdx.x, lane = tid & 63, wave = tid >> 6;
    const int lr = lane & 15, lc = lane >> 4;
    const int q0 = qt * 128;
    const int qw = q0 + wave * 16;

    __shared__ __align__(16) unsigned short sK[2][64 * 64];   // chunk-XOR swizzled
    __shared__ __align__(16) unsigned short sVt[2][64][72];   // V^T; flat [128][72] in epilogue

    const unsigned short* Qh = Q + (((size_t)b * 32 + h) * 2048) * 64;
    const unsigned short* Kh = K + (((size_t)b * 8 + kvh) * 2048) * 64;
    const unsigned short* Vh = V + (((size_t)b * 8 + kvh) * 2048) * 64;

    // ---- load Q frags + in-register RoPE
    const int qglob = qw + lr;
    bf16x8 qf0, qf1;
    {
        const bf16x8 qr0 = *(const bf16x8*)&Qh[(size_t)qglob * 64 + lc * 8];
        const bf16x8 qr1 = *(const bf16x8*)&Qh[(size_t)qglob * 64 + 32 + lc * 8];
        const int s32 = qglob << 5;
        const float4 a0 = *(const float4*)&fc[(s32 + lc * 4) << 1];
        const float4 a1 = *(const float4*)&fc[((s32 + lc * 4) << 1) + 4];
        const float4 b0 = *(const float4*)&fc[(s32 + 16 + lc * 4) << 1];
        const float4 b1 = *(const float4*)&fc[((s32 + 16 + lc * 4) << 1) + 4];
        auto rot = [&](bf16x8 q, float4 cs0, float4 cs1) -> bf16x8 {
            union { bf16x8 v; unsigned int w[4]; } u;
            u.v = q;
            const float c[4] = {cs0.x, cs0.z, cs1.x, cs1.z};
            const float sn[4] = {cs0.y, cs0.w, cs1.y, cs1.w};
#pragma unroll
            for (int t = 0; t < 4; t++) {
                const float t0 = bf2f((unsigned short)(u.w[t] & 0xffffu));
                const float t1 = bf2f((unsigned short)(u.w[t] >> 16));
                u.w[t] = pack_bf2(fmaf(t0, c[t], -t1 * sn[t]), fmaf(t0, sn[t], t1 * c[t]));
            }
            return u.v;
        };
        qf0 = rot(qr0, a0, a1);
        qf1 = rot(qr1, b0, b1);
    }

    const int dsl = dstart[b * 2048 + qglob];
    const int ds_wmin = dstart[b * 2048 + qw];
    const int t0 = dstart[b * 2048 + q0] & ~63;

    const int w8 = wave * 8;
    const int kr = tid >> 3, kc = tid & 7; // 512 threads cover the 64x64 K tile

    auto STAGE_K = [&](int t, int c) {
        gload_lds16(Kh + (size_t)(t + kr) * 64 + ((kc ^ (kr & 7)) * 8), &sK[c][tid * 8]);
    };
    auto WRITE_V = [&](const uint4& va, int c) {
        const unsigned short* pa = (const unsigned short*)&va;
#pragma unroll
        for (int e = 0; e < 8; e++) sVt[c][w8 + e][lane] = pa[e];
    };

    float mrow = -1e30f, lrow = 0.f;
    f32x4 oacc[4];
#pragma unroll
    for (int j = 0; j < 4; j++) oacc[j] = (f32x4){0.f, 0.f, 0.f, 0.f};

    // ---- prologue: stage tile t0 into buf 0
    STAGE_K(t0, 0);
    {
        const uint4 va = *(const uint4*)&Vh[(size_t)(t0 + lane) * 64 + w8];
        asm volatile("s_waitcnt vmcnt(0)" ::: "memory");
        WRITE_V(va, 0);
    }
    __syncthreads();

    int cb = 0;
    for (int t = t0; t < q0 + 128; t += 64, cb ^= 1) {
        const bool more = (t < q0 + 64); // block-uniform
        uint4 va;
        if (more) {
            STAGE_K(t + 64, cb ^ 1);
            va = *(const uint4*)&Vh[(size_t)(t + 64 + lane) * 64 + w8];
        }
        const bool act = !(t > qw + 15 || t + 63 < ds_wmin); // wave-uniform
        union { unsigned int w[4]; bf16x8 v; } B0, B1;

        if (act) {
            // --- QK^T swapped: C[k][q], k = kk*16 + lc*4 + r, q = qw + lr
            f32x4 sc[4];
#pragma unroll
            for (int kk = 0; kk < 4; kk++) {
                const int krow = kk * 16 + lr;
                const bf16x8 kf0 = *(const bf16x8*)&sK[cb][krow * 64 + ((lc ^ (lr & 7)) * 8)];
                const bf16x8 kf1 = *(const bf16x8*)&sK[cb][krow * 64 + (((4 + lc) ^ (lr & 7)) * 8)];
                f32x4 a = (f32x4){0.f, 0.f, 0.f, 0.f};
                a = MFMA16(kf0, qf0, a);
                a = MFMA16(kf1, qf1, a);
                sc[kk] = a;
            }
            // --- mask + scale + in-lane softmax
            float vmax = -3e38f;
#pragma unroll
            for (int kk = 0; kk < 4; kk++)
#pragma unroll
                for (int r = 0; r < 4; r++) {
                    const int kpos = t + kk * 16 + lc * 4 + r;
                    const bool okm = (kpos <= qglob) && (kpos >= dsl);
                    sc[kk][r] = okm ? sc[kk][r] * 0.125f : -3e38f;
                    vmax = fmaxf(vmax, sc[kk][r]);
                }
            vmax = fmaxf(vmax, __shfl_xor(vmax, 16));
            vmax = fmaxf(vmax, __shfl_xor(vmax, 32));
            const float mnew = fmaxf(mrow, vmax);
            const float corr = __expf(mrow - mnew);
            mrow = mnew;

            float rsum = 0.f;
            unsigned int pk[4][2];
#pragma unroll
            for (int kk = 0; kk < 4; kk++) {
                const float p0 = __expf(sc[kk][0] - mnew);
                const float p1 = __expf(sc[kk][1] - mnew);
                const float p2 = __expf(sc[kk][2] - mnew);
                const float p3 = __expf(sc[kk][3] - mnew);
                rsum += (p0 + p1) + (p2 + p3);
                pk[kk][0] = pack_bf2(p0, p1);
                pk[kk][1] = pack_bf2(p2, p3);
            }
            rsum += __shfl_xor(rsum, 16);
            rsum += __shfl_xor(rsum, 32);
            lrow = lrow * corr + rsum;
#pragma unroll
            for (int j = 0; j < 4; j++)
#pragma unroll
                for (int r = 0; r < 4; r++) oacc[j][r] *= corr;

            // --- redistribute P -> PV B-frags (shuffle both kk candidates, select by dest lc>>1)
            const int srcEven = 32 * (lc & 1) + lr;
            const int srcOdd  = srcEven + 16;
            const bool hiKK = (lc & 2) != 0;
            unsigned int a, c;
            a = __shfl(pk[0][0], srcEven); c = __shfl(pk[1][0], srcEven); B0.w[0] = hiKK ? c : a;
            a = __shfl(pk[0][1], srcEven); c = __shfl(pk[1][1], srcEven); B0.w[1] = hiKK ? c : a;
            a = __shfl(pk[0][0], srcOdd);  c = __shfl(pk[1][0], srcOdd);  B0.w[2] = hiKK ? c : a;
            a = __shfl(pk[0][1], srcOdd);  c = __shfl(pk[1][1], srcOdd);  B0.w[3] = hiKK ? c : a;
            a = __shfl(pk[2][0], srcEven); c = __shfl(pk[3][0], srcEven); B1.w[0] = hiKK ? c : a;
            a = __shfl(pk[2][1], srcEven); c = __shfl(pk[3][1], srcEven); B1.w[1] = hiKK ? c : a;
            a = __shfl(pk[2][0], srcOdd);  c = __shfl(pk[3][0], srcOdd);  B1.w[2] = hiKK ? c : a;
            a = __shfl(pk[2][1], srcOdd);  c = __shfl(pk[3][1], srcOdd);  B1.w[3] = hiKK ? c : a;
        }

        if (more) {
            asm volatile("s_waitcnt vmcnt(0)" ::: "memory"); // V(t+64) regs + K(t+64) LDS landed
            WRITE_V(va, cb ^ 1);
        }

        if (act) {
            // --- PV: O^T = V^T x P^T, C[d][q]: d = j*16 + lc*4 + r, q = qw + lr
#pragma unroll
            for (int j = 0; j < 4; j++) {
                const bf16x8 a0 = *(const bf16x8*)&sVt[cb][j * 16 + lr][lc * 8];
                const bf16x8 a1 = *(const bf16x8*)&sVt[cb][j * 16 + lr][32 + lc * 8];
                oacc[j] = MFMA16(a0, B0.v, oacc[j]);
                oacc[j] = MFMA16(a1, B1.v, oacc[j]);
            }
        }
        __syncthreads();
    }

    // --- epilogue: transpose via LDS (sVt viewed as flat [128][72]), coalesced stores
    unsigned short (*E)[72] = (unsigned short (*)[72])&sVt[0][0][0];
    const float inv = 1.0f / lrow;
#pragma unroll
    for (int j = 0; j < 4; j++)
#pragma unroll
        for (int p = 0; p < 2; p++) {
            const unsigned int w = pack_bf2(oacc[j][2 * p] * inv, oacc[j][2 * p + 1] * inv);
            *(unsigned int*)&E[wave * 16 + lr][j * 16 + lc * 4 + 2 * p] = w;
        }
    __syncthreads();
#pragma unroll
    for (int half = 0; half < 2; half++) {
        const int c = lane + 64 * half;
        const int row = c >> 3, ch = c & 7;
        const uint4 o = *(const uint4*)&E[wave * 16 + row][ch * 8];
        *(uint4*)&AO[((size_t)b * 2048 + qw + row) * 2048 + h * 64 + ch * 8] = o;
    }
}

// ---------------------------------------------------------------- host
extern "C" void kernel_launch(void* const* d_in, const int* in_sizes, int n_in,
                              void* d_out, int out_size, void* d_ws, size_t ws_size,
                              hipStream_t stream) {
    const float* x  = (const float*)d_in[0];
    const float* fc = (const float*)d_in[1];
    const int* sid  = (const int*)d_in[2];
    const float* wq = (const float*)d_in[3];
    const float* wk = (const float*)d_in[4];
    const float* wv = (const float*)d_in[5];
    const float* wo = (const float*)d_in[6];
    float* out = (float*)d_out;

    unsigned short* xb   = (unsigned short*)d_ws;
    unsigned short* wqkv = xb + (size_t)4096 * 2048;
    unsigned short* wob  = wqkv + (size_t)3072 * 2048;
    unsigned short* Qb   = wob + (size_t)2048 * 2048;
    unsigned short* Kb   = Qb + (size_t)2 * 32 * 2048 * 64;
    unsigned short* Vb   = Kb + (size_t)2 * 8 * 2048 * 64;
    unsigned short* AO   = Vb + (size_t)2 * 8 * 2048 * 64;
    int* dstart = (int*)(AO + (size_t)4096 * 2048);

    cvt_all_kernel<<<18432, 256, 0, stream>>>(x, wq, wk, wv, wo, xb, wqkv, wob);
    docstart_kernel<<<16, 256, 0, stream>>>(sid, dstart);
    gemm_qkv8<<<dim3(192), 512, 0, stream>>>(xb, wqkv, Qb, Kb, Vb);
    rope_k_kernel<<<1024, 256, 0, stream>>>(Kb, fc);
    attn_kernel<<<dim3(16, 32, 2), 512, 0, stream>>>(Qb, Kb, Vb, dstart, fc, AO);
    gemm_bt<1><<<dim3(16, 32), 256, 0, stream>>>(AO, wob, 2048, 2048, nullptr, nullptr, nullptr, out);
}

// Round 16
// 184.809 us; speedup vs baseline: 1.0803x; 1.0419x over previous
//
#include <hip/hip_runtime.h>
#include <hip/hip_bf16.h>

typedef __attribute__((ext_vector_type(8))) short bf16x8;
typedef __attribute__((ext_vector_type(4))) float f32x4;

#define MFMA16(A, B, C) __builtin_amdgcn_mfma_f32_16x16x32_bf16(A, B, C, 0, 0, 0)

__device__ __forceinline__ unsigned short f2bf(float f) {
    unsigned int u = __float_as_uint(f);
    u += 0x7fffu + ((u >> 16) & 1u);
    return (unsigned short)(u >> 16);
}
__device__ __forceinline__ float bf2f(unsigned short h) {
    return __uint_as_float(((unsigned int)h) << 16);
}
__device__ __forceinline__ unsigned int pack_bf2(float lo, float hi) {
    __hip_bfloat162 h = __float22bfloat162_rn(make_float2(lo, hi)); // v_cvt_pk_bf16_f32
    return *reinterpret_cast<unsigned int*>(&h);
}

__device__ __forceinline__ void gload_lds16(const void* g, void* l) {
    __builtin_amdgcn_global_load_lds(
        (__attribute__((address_space(1))) unsigned int*)g,
        (__attribute__((address_space(3))) unsigned int*)l, 16, 0, 0);
}

// LDS swizzle for [rows][64 bf16] regions (128 B/row): XOR 16B-chunk with row&7.
__device__ __forceinline__ int swz128(int by) {
    return by ^ (((by >> 7) & 7) << 4);
}

// ---------------------------------------------------------------- fused converts (1 launch)
__global__ void cvt_all_kernel(const float* __restrict__ x,  const float* __restrict__ wq,
                               const float* __restrict__ wk, const float* __restrict__ wv,
                               const float* __restrict__ wo,
                               unsigned short* __restrict__ xb,
                               unsigned short* __restrict__ wqkv,
                               unsigned short* __restrict__ wob) {
    const int i = blockIdx.x * 256 + threadIdx.x; // 0 .. 4718591 (float4 units)
    const float* src;
    unsigned short* dst;
    int off;
    if (i < 2097152)      { src = x;  dst = xb;   off = i; }
    else if (i < 3145728) { src = wq; dst = wqkv; off = i - 2097152; }
    else if (i < 3407872) { src = wk; dst = wqkv + (size_t)2048 * 2048; off = i - 3145728; }
    else if (i < 3670016) { src = wv; dst = wqkv + (size_t)2560 * 2048; off = i - 3407872; }
    else                  { src = wo; dst = wob;  off = i - 3670016; }
    const float4 v = ((const float4*)src)[off];
    uint2 o;
    o.x = pack_bf2(v.x, v.y);
    o.y = pack_bf2(v.z, v.w);
    ((uint2*)dst)[off] = o;
}

// ---------------------------------------------------------------- doc starts
__global__ void docstart_kernel(const int* __restrict__ sid, int* __restrict__ ds) {
    const int i = blockIdx.x * 256 + threadIdx.x; // 0..4095
    const int b = i >> 11, s = i & 2047;
    const int* row = sid + b * 2048;
    const int v = row[s];
    int lo = 0, hi = s;
    while (lo < hi) { const int mid = (lo + hi) >> 1; if (row[mid] < v) lo = mid + 1; else hi = mid; }
    ds[i] = lo;
}

// ---------------------------------------------------------------- QKV 256x192 GEMM, verified 8-phase schedule
// Grid 16x16 = 256 blocks = 100% CU coverage. RACE FIX vs round 15: B1 bytes now have a
// SINGLE writer. Waves 0-3 write the live B1 quarter; waves 4-7 issue their 2nd load into
// a dead per-wave scratch region (same global source) so the per-wave load count — and
// therefore the verified vmcnt ledger — is unchanged. Concurrent same-address DMA
// write-write (round 15's only unordered pair) is eliminated.
#define QKV_K 2048
#define QKV_NT 32
__global__ __launch_bounds__(512, 2) void gemm_qkv8(
    const unsigned short* __restrict__ A,
    const unsigned short* __restrict__ B,
    unsigned short* __restrict__ oq,
    unsigned short* __restrict__ ok,
    unsigned short* __restrict__ ov)
{
    __shared__ __align__(16) unsigned short S[2][28672]; // 112 KiB live
    __shared__ __align__(16) unsigned short Sx[2048];    // 4 KiB dead scratch (waves 4-7 dup loads)
    const int tid = threadIdx.x, lane = tid & 63, w = tid >> 6;
    const int wr = w >> 1, wc = w & 1;
    const int lr = lane & 15, lc = lane >> 4;

    // XCD swizzle over 256 blocks (256 % 8 == 0)
    int bid = blockIdx.x;
    bid = (bid & 7) * 32 + (bid >> 3);
    const int m0 = (bid >> 4) * 256, n0 = (bid & 15) * 192;

    // staging geometry: linear LDS dest, inverse-swizzled global source (rule #21)
    const int oA0 = (w << 11) + (lane << 4);              // A half: 16 KB (8 waves x 2 KB)
    const int oA1 = oA0 + 1024;
    const int oB0 = (w << 10) + (lane << 4);              // B half bytes 0..8191 (8 waves x 1 KB)
    const int oB1 = 8192 + ((w & 3) << 10) + (lane << 4); // B half bytes 8192..12287 (waves 0-3 only)
    const int oBx = ((w & 3) << 10) + (lane << 4);        // scratch slot for waves 4-7
    const int vA0 = swz128(oA0), vA1 = swz128(oA1);
    const int vB0 = swz128(oB0), vB1 = swz128(oB1);
    const size_t aoff0 = (size_t)(m0 + (vA0 >> 7)) * QKV_K + ((vA0 & 127) >> 1);
    const size_t aoff1 = (size_t)(m0 + (vA1 >> 7)) * QKV_K + ((vA1 & 127) >> 1);
    const size_t boff0 = (size_t)(n0 + (vB0 >> 7)) * QKV_K + ((vB0 & 127) >> 1);
    const size_t boff1 = (size_t)(n0 + (vB1 >> 7)) * QKV_K + ((vB1 & 127) >> 1);
    const bool liveB1 = (w < 4); // wave-uniform

    f32x4 acc[2][2][2][3];
#pragma unroll
    for (int a = 0; a < 2; a++)
#pragma unroll
        for (int bq = 0; bq < 2; bq++)
#pragma unroll
            for (int i = 0; i < 2; i++)
#pragma unroll
                for (int j = 0; j < 3; j++) acc[a][bq][i][j] = (f32x4){0.f, 0.f, 0.f, 0.f};

    bf16x8 Af[2][2], Bf0[3][2], Bf1[3][2];

    auto STAGE_A = [&](int bf, int h, int kt) {
        const unsigned short* src = A + (size_t)h * 128 * QKV_K + (size_t)kt * 64;
        char* dst = (char*)&S[bf][0] + h * 16384;
        gload_lds16(src + aoff0, dst + oA0);
        gload_lds16(src + aoff1, dst + oA1);
    };
    auto STAGE_B = [&](int bf, int h, int kt) {
        const unsigned short* src = B + (size_t)h * 96 * QKV_K + (size_t)kt * 64;
        char* dst = (char*)&S[bf][0] + 32768 + h * 12288;
        gload_lds16(src + boff0, dst + oB0);
        gload_lds16(src + boff1, liveB1 ? (dst + oB1) : ((char*)Sx + oBx));
    };
    auto LDA = [&](int bf, int mh) {
#pragma unroll
        for (int i = 0; i < 2; i++)
#pragma unroll
            for (int kh = 0; kh < 2; kh++) {
                const int by = swz128(((wr * 32 + i * 16 + lr) << 7) + (kh << 6) + (lc << 4));
                Af[i][kh] = *(const bf16x8*)((const char*)&S[bf][0] + mh * 16384 + by);
            }
    };
    auto LDB = [&](int bf, int nh, bf16x8 (&Bf)[3][2]) {
#pragma unroll
        for (int j = 0; j < 3; j++)
#pragma unroll
            for (int kh = 0; kh < 2; kh++) {
                const int by = swz128(((wc * 48 + j * 16 + lr) << 7) + (kh << 6) + (lc << 4));
                Bf[j][kh] = *(const bf16x8*)((const char*)&S[bf][0] + 32768 + nh * 12288 + by);
            }
    };
    auto QUAD = [&](f32x4 (&ac)[2][3], bf16x8 (&Bf)[3][2]) {
        __builtin_amdgcn_s_setprio(1);
#pragma unroll
        for (int i = 0; i < 2; i++)
#pragma unroll
            for (int j = 0; j < 3; j++)
#pragma unroll
                for (int kh = 0; kh < 2; kh++)
                    ac[i][j] = MFMA16(Af[i][kh], Bf[j][kh], ac[i][j]);
        __builtin_amdgcn_s_setprio(0);
    };

#define BAR() __builtin_amdgcn_s_barrier()
#define LGKM0() asm volatile("s_waitcnt lgkmcnt(0)" ::: "memory")

    // ---- prologue: tile0 (A0,A1,B0,B1)->buf0; A0[1],B1[1],A1[1]->buf1; drain to 3 stages
    STAGE_A(0, 0, 0); STAGE_A(0, 1, 0); STAGE_B(0, 0, 0); STAGE_B(0, 1, 0);
    STAGE_A(1, 0, 1); STAGE_B(1, 1, 1); STAGE_A(1, 1, 1);
    asm volatile("s_waitcnt vmcnt(6)" ::: "memory");
    BAR();

    auto GROUP = [&](int g, int bf) {
        // ph1: quadrant (0,0); stage B0[g+1] -> other buf
        LDA(bf, 0); LDB(bf, 0, Bf0);
        if (g + 1 < QKV_NT) STAGE_B(bf ^ 1, 0, g + 1);
        BAR(); LGKM0();
        QUAD(acc[0][0], Bf0);
        BAR();
        // ph2: (0,1); stage A0[g+2] -> current buf
        LDB(bf, 1, Bf1);
        if (g + 2 < QKV_NT) STAGE_A(bf, 0, g + 2);
        BAR(); LGKM0();
        QUAD(acc[0][1], Bf1);
        BAR();
        // ph3: (1,1); stage B1[g+2] -> current buf
        LDA(bf, 1);
        if (g + 2 < QKV_NT) STAGE_B(bf, 1, g + 2);
        BAR(); LGKM0();
        QUAD(acc[1][1], Bf1);
        BAR();
        // ph4: (1,0); stage A1[g+2] -> current buf
        if (g + 2 < QKV_NT) STAGE_A(bf, 1, g + 2);
        BAR();
        QUAD(acc[1][0], Bf0);
        if (g == QKV_NT - 2) { asm volatile("s_waitcnt vmcnt(0)" ::: "memory"); }
        else                 { asm volatile("s_waitcnt vmcnt(6)" ::: "memory"); }
        BAR();
    };

#pragma unroll 1
    for (int g = 0; g < QKV_NT; g += 2) {
        GROUP(g, 0);
        GROUP(g + 1, 1);
    }

    // ---- epilogue: scatter into Q:(B,32,S,64), K/V:(B,8,S,64) bf16
#pragma unroll
    for (int mh = 0; mh < 2; mh++)
#pragma unroll
        for (int nh = 0; nh < 2; nh++)
#pragma unroll
            for (int i = 0; i < 2; i++)
#pragma unroll
                for (int j = 0; j < 3; j++) {
                    const int n = n0 + nh * 96 + wc * 48 + j * 16 + lr;
                    const int d = n & 63;
                    const int hh6 = n >> 6;
#pragma unroll
                    for (int r = 0; r < 4; r++) {
                        const int m = m0 + mh * 128 + wr * 32 + i * 16 + lc * 4 + r;
                        const int bb = m >> 11, s = m & 2047;
                        const unsigned short val = f2bf(acc[mh][nh][i][j][r]);
                        if (n < 2048) {
                            oq[((((size_t)bb * 32 + hh6) * 2048 + s) << 6) + d] = val;
                        } else if (n < 2560) {
                            ok[((((size_t)bb * 8 + (hh6 - 32)) * 2048 + s) << 6) + d] = val;
                        } else {
                            ov[((((size_t)bb * 8 + (hh6 - 40)) * 2048 + s) << 6) + d] = val;
                        }
                    }
                }
}
#undef BAR
#undef LGKM0

// ---------------------------------------------------------------- RoPE on K only (Q fused into attn), 4 pairs/thread
__global__ void rope_k_kernel(unsigned short* __restrict__ Kb,
                              const float* __restrict__ fc)
{
    const int j = blockIdx.x * 256 + threadIdx.x; // 0 .. 262143
    const int g = j & 7, s = (j >> 3) & 2047, bh = j >> 14; // bh in 0..15
    const size_t off = (((size_t)bh * 2048 + s) << 6) + g * 8;
    uint4 u = *(uint4*)&Kb[off];
    const float4 cs0 = *(const float4*)&fc[((s << 5) + g * 4) << 1];       // c0 s0 c1 s1
    const float4 cs1 = *(const float4*)&fc[(((s << 5) + g * 4) << 1) + 4]; // c2 s2 c3 s3
    unsigned int* uw = (unsigned int*)&u;
    float c[4] = {cs0.x, cs0.z, cs1.x, cs1.z};
    float sn[4] = {cs0.y, cs0.w, cs1.y, cs1.w};
#pragma unroll
    for (int q = 0; q < 4; q++) {
        const float t0 = bf2f((unsigned short)(uw[q] & 0xffffu));
        const float t1 = bf2f((unsigned short)(uw[q] >> 16));
        uw[q] = pack_bf2(fmaf(t0, c[q], -t1 * sn[q]), fmaf(t0, sn[q], t1 * c[q]));
    }
    *(uint4*)&Kb[off] = u;
}

// ---------------------------------------------------------------- bt-GEMM (m97, round-10 verified) for out-proj
template <int EPI>
__global__ __launch_bounds__(256) void gemm_bt(
    const unsigned short* __restrict__ A,
    const unsigned short* __restrict__ B,
    int K, int N,
    unsigned short* __restrict__ oq,
    unsigned short* __restrict__ ok,
    unsigned short* __restrict__ ov,
    float* __restrict__ of)
{
    __shared__ __align__(16) unsigned short sA[128 * 32];
    __shared__ __align__(16) unsigned short sB[128 * 32];
    const int tid = threadIdx.x;
    const int lane = tid & 63, wave = tid >> 6;
    const int wr = wave >> 1, wc = wave & 1;
    const int lr = lane & 15, lc = lane >> 4;

    int bid = blockIdx.y * gridDim.x + blockIdx.x;
    const int cpx = (gridDim.x * gridDim.y) >> 3;
    bid = (bid & 7) * cpx + (bid >> 3);
    const int m0 = (bid / gridDim.x) * 128, n0 = (bid % gridDim.x) * 128;

    f32x4 acc[4][4];
#pragma unroll
    for (int i = 0; i < 4; i++)
#pragma unroll
        for (int j = 0; j < 4; j++) acc[i][j] = (f32x4){0.f, 0.f, 0.f, 0.f};

    const int u0 = tid, u1 = tid + 256;
    for (int k0 = 0; k0 < K; k0 += 32) {
        __syncthreads();
        gload_lds16(A + (size_t)(m0 + (u0 >> 2)) * K + k0 + (u0 & 3) * 8, &sA[u0 * 8]);
        gload_lds16(A + (size_t)(m0 + (u1 >> 2)) * K + k0 + (u1 & 3) * 8, &sA[u1 * 8]);
        gload_lds16(B + (size_t)(n0 + (u0 >> 2)) * K + k0 + (u0 & 3) * 8, &sB[u0 * 8]);
        gload_lds16(B + (size_t)(n0 + (u1 >> 2)) * K + k0 + (u1 & 3) * 8, &sB[u1 * 8]);
        __syncthreads();
        bf16x8 af[4], bfv[4];
#pragma unroll
        for (int i = 0; i < 4; i++) {
            af[i]  = *(const bf16x8*)&sA[(wr * 64 + i * 16 + lr) * 32 + lc * 8];
            bfv[i] = *(const bf16x8*)&sB[(wc * 64 + i * 16 + lr) * 32 + lc * 8];
        }
#pragma unroll
        for (int i = 0; i < 4; i++)
#pragma unroll
            for (int j = 0; j < 4; j++) acc[i][j] = MFMA16(af[i], bfv[j], acc[i][j]);
    }

    if (EPI == 0) {
#pragma unroll
        for (int i = 0; i < 4; i++) {
#pragma unroll
            for (int j = 0; j < 4; j++) {
                const int n = n0 + wc * 64 + j * 16 + lr;
                const int d = n & 63;
#pragma unroll
                for (int r = 0; r < 4; r++) {
                    const int m = m0 + wr * 64 + i * 16 + lc * 4 + r;
                    const int bb = m >> 11, s = m & 2047;
                    const unsigned short val = f2bf(acc[i][j][r]);
                    if (n < 2048) {
                        const int hh = n >> 6;
                        oq[((((size_t)bb * 32 + hh) * 2048 + s) << 6) + d] = val;
                    } else if (n < 2560) {
                        const int hh = (n >> 6) - 32;
                        ok[((((size_t)bb * 8 + hh) * 2048 + s) << 6) + d] = val;
                    } else {
                        const int hh = (n >> 6) - 40;
                        ov[((((size_t)bb * 8 + hh) * 2048 + s) << 6) + d] = val;
                    }
                }
            }
        }
    } else {
#pragma unroll
        for (int i = 0; i < 4; i++)
#pragma unroll
            for (int j = 0; j < 4; j++)
#pragma unroll
                for (int r = 0; r < 4; r++) {
                    const int m = m0 + wr * 64 + i * 16 + lc * 4 + r;
                    const int n = n0 + wc * 64 + j * 16 + lr;
                    of[(size_t)m * N + n] = acc[i][j][r];
                }
    }
}

// ---------------------------------------------------------------- flash attention v8 (round-14 verified): QBLK=128 + fused Q-RoPE
__global__ __launch_bounds__(512) void attn_kernel(
    const unsigned short* __restrict__ Q,
    const unsigned short* __restrict__ K,
    const unsigned short* __restrict__ V,
    const int* __restrict__ dstart,
    const float* __restrict__ fc,
    unsigned short* __restrict__ AO)
{
    const int qt = 15 - blockIdx.x; // heavy blocks first
    const int h = blockIdx.y, b = blockIdx.z;
    const int kvh = h >> 2;
    const int tid = threadIdx.x, lane = tid & 63, wave = tid >> 6;
    const int lr = lane & 15, lc = lane >> 4;
    const int q0 = qt * 128;
    const int qw = q0 + wave * 16;

    __shared__ __align__(16) unsigned short sK[2][64 * 64];   // chunk-XOR swizzled
    __shared__ __align__(16) unsigned short sVt[2][64][72];   // V^T; flat [128][72] in epilogue

    const unsigned short* Qh = Q + (((size_t)b * 32 + h) * 2048) * 64;
    const unsigned short* Kh = K + (((size_t)b * 8 + kvh) * 2048) * 64;
    const unsigned short* Vh = V + (((size_t)b * 8 + kvh) * 2048) * 64;

    // ---- load Q frags + in-register RoPE
    const int qglob = qw + lr;
    bf16x8 qf0, qf1;
    {
        const bf16x8 qr0 = *(const bf16x8*)&Qh[(size_t)qglob * 64 + lc * 8];
        const bf16x8 qr1 = *(const bf16x8*)&Qh[(size_t)qglob * 64 + 32 + lc * 8];
        const int s32 = qglob << 5;
        const float4 a0 = *(const float4*)&fc[(s32 + lc * 4) << 1];
        const float4 a1 = *(const float4*)&fc[((s32 + lc * 4) << 1) + 4];
        const float4 b0 = *(const float4*)&fc[(s32 + 16 + lc * 4) << 1];
        const float4 b1 = *(const float4*)&fc[((s32 + 16 + lc * 4) << 1) + 4];
        auto rot = [&](bf16x8 q, float4 cs0, float4 cs1) -> bf16x8 {
            union { bf16x8 v; unsigned int w[4]; } u;
            u.v = q;
            const float c[4] = {cs0.x, cs0.z, cs1.x, cs1.z};
            const float sn[4] = {cs0.y, cs0.w, cs1.y, cs1.w};
#pragma unroll
            for (int t = 0; t < 4; t++) {
                const float t0 = bf2f((unsigned short)(u.w[t] & 0xffffu));
                const float t1 = bf2f((unsigned short)(u.w[t] >> 16));
                u.w[t] = pack_bf2(fmaf(t0, c[t], -t1 * sn[t]), fmaf(t0, sn[t], t1 * c[t]));
            }
            return u.v;
        };
        qf0 = rot(qr0, a0, a1);
        qf1 = rot(qr1, b0, b1);
    }

    const int dsl = dstart[b * 2048 + qglob];
    const int ds_wmin = dstart[b * 2048 + qw];
    const int t0 = dstart[b * 2048 + q0] & ~63;

    const int w8 = wave * 8;
    const int kr = tid >> 3, kc = tid & 7; // 512 threads cover the 64x64 K tile

    auto STAGE_K = [&](int t, int c) {
        gload_lds16(Kh + (size_t)(t + kr) * 64 + ((kc ^ (kr & 7)) * 8), &sK[c][tid * 8]);
    };
    auto WRITE_V = [&](const uint4& va, int c) {
        const unsigned short* pa = (const unsigned short*)&va;
#pragma unroll
        for (int e = 0; e < 8; e++) sVt[c][w8 + e][lane] = pa[e];
    };

    float mrow = -1e30f, lrow = 0.f;
    f32x4 oacc[4];
#pragma unroll
    for (int j = 0; j < 4; j++) oacc[j] = (f32x4){0.f, 0.f, 0.f, 0.f};

    // ---- prologue: stage tile t0 into buf 0
    STAGE_K(t0, 0);
    {
        const uint4 va = *(const uint4*)&Vh[(size_t)(t0 + lane) * 64 + w8];
        asm volatile("s_waitcnt vmcnt(0)" ::: "memory");
        WRITE_V(va, 0);
    }
    __syncthreads();

    int cb = 0;
    for (int t = t0; t < q0 + 128; t += 64, cb ^= 1) {
        const bool more = (t < q0 + 64); // block-uniform
        uint4 va;
        if (more) {
            STAGE_K(t + 64, cb ^ 1);
            va = *(const uint4*)&Vh[(size_t)(t + 64 + lane) * 64 + w8];
        }
        const bool act = !(t > qw + 15 || t + 63 < ds_wmin); // wave-uniform
        union { unsigned int w[4]; bf16x8 v; } B0, B1;

        if (act) {
            // --- QK^T swapped: C[k][q], k = kk*16 + lc*4 + r, q = qw + lr
            f32x4 sc[4];
#pragma unroll
            for (int kk = 0; kk < 4; kk++) {
                const int krow = kk * 16 + lr;
                const bf16x8 kf0 = *(const bf16x8*)&sK[cb][krow * 64 + ((lc ^ (lr & 7)) * 8)];
                const bf16x8 kf1 = *(const bf16x8*)&sK[cb][krow * 64 + (((4 + lc) ^ (lr & 7)) * 8)];
                f32x4 a = (f32x4){0.f, 0.f, 0.f, 0.f};
                a = MFMA16(kf0, qf0, a);
                a = MFMA16(kf1, qf1, a);
                sc[kk] = a;
            }
            // --- mask + scale + in-lane softmax
            float vmax = -3e38f;
#pragma unroll
            for (int kk = 0; kk < 4; kk++)
#pragma unroll
                for (int r = 0; r < 4; r++) {
                    const int kpos = t + kk * 16 + lc * 4 + r;
                    const bool okm = (kpos <= qglob) && (kpos >= dsl);
                    sc[kk][r] = okm ? sc[kk][r] * 0.125f : -3e38f;
                    vmax = fmaxf(vmax, sc[kk][r]);
                }
            vmax = fmaxf(vmax, __shfl_xor(vmax, 16));
            vmax = fmaxf(vmax, __shfl_xor(vmax, 32));
            const float mnew = fmaxf(mrow, vmax);
            const float corr = __expf(mrow - mnew);
            mrow = mnew;

            float rsum = 0.f;
            unsigned int pk[4][2];
#pragma unroll
            for (int kk = 0; kk < 4; kk++) {
                const float p0 = __expf(sc[kk][0] - mnew);
                const float p1 = __expf(sc[kk][1] - mnew);
                const float p2 = __expf(sc[kk][2] - mnew);
                const float p3 = __expf(sc[kk][3] - mnew);
                rsum += (p0 + p1) + (p2 + p3);
                pk[kk][0] = pack_bf2(p0, p1);
                pk[kk][1] = pack_bf2(p2, p3);
            }
            rsum += __shfl_xor(rsum, 16);
            rsum += __shfl_xor(rsum, 32);
            lrow = lrow * corr + rsum;
#pragma unroll
            for (int j = 0; j < 4; j++)
#pragma unroll
                for (int r = 0; r < 4; r++) oacc[j][r] *= corr;

            // --- redistribute P -> PV B-frags (shuffle both kk candidates, select by dest lc>>1)
            const int srcEven = 32 * (lc & 1) + lr;
            const int srcOdd  = srcEven + 16;
            const bool hiKK = (lc & 2) != 0;
            unsigned int a, c;
            a = __shfl(pk[0][0], srcEven); c = __shfl(pk[1][0], srcEven); B0.w[0] = hiKK ? c : a;
            a = __shfl(pk[0][1], srcEven); c = __shfl(pk[1][1], srcEven); B0.w[1] = hiKK ? c : a;
            a = __shfl(pk[0][0], srcOdd);  c = __shfl(pk[1][0], srcOdd);  B0.w[2] = hiKK ? c : a;
            a = __shfl(pk[0][1], srcOdd);  c = __shfl(pk[1][1], srcOdd);  B0.w[3] = hiKK ? c : a;
            a = __shfl(pk[2][0], srcEven); c = __shfl(pk[3][0], srcEven); B1.w[0] = hiKK ? c : a;
            a = __shfl(pk[2][1], srcEven); c = __shfl(pk[3][1], srcEven); B1.w[1] = hiKK ? c : a;
            a = __shfl(pk[2][0], srcOdd);  c = __shfl(pk[3][0], srcOdd);  B1.w[2] = hiKK ? c : a;
            a = __shfl(pk[2][1], srcOdd);  c = __shfl(pk[3][1], srcOdd);  B1.w[3] = hiKK ? c : a;
        }

        if (more) {
            asm volatile("s_waitcnt vmcnt(0)" ::: "memory"); // V(t+64) regs + K(t+64) LDS landed
            WRITE_V(va, cb ^ 1);
        }

        if (act) {
            // --- PV: O^T = V^T x P^T, C[d][q]: d = j*16 + lc*4 + r, q = qw + lr
#pragma unroll
            for (int j = 0; j < 4; j++) {
                const bf16x8 a0 = *(const bf16x8*)&sVt[cb][j * 16 + lr][lc * 8];
                const bf16x8 a1 = *(const bf16x8*)&sVt[cb][j * 16 + lr][32 + lc * 8];
                oacc[j] = MFMA16(a0, B0.v, oacc[j]);
                oacc[j] = MFMA16(a1, B1.v, oacc[j]);
            }
        }
        __syncthreads();
    }

    // --- epilogue: transpose via LDS (sVt viewed as flat [128][72]), coalesced stores
    unsigned short (*E)[72] = (unsigned short (*)[72])&sVt[0][0][0];
    const float inv = 1.0f / lrow;
#pragma unroll
    for (int j = 0; j < 4; j++)
#pragma unroll
        for (int p = 0; p < 2; p++) {
            const unsigned int w = pack_bf2(oacc[j][2 * p] * inv, oacc[j][2 * p + 1] * inv);
            *(unsigned int*)&E[wave * 16 + lr][j * 16 + lc * 4 + 2 * p] = w;
        }
    __syncthreads();
#pragma unroll
    for (int half = 0; half < 2; half++) {
        const int c = lane + 64 * half;
        const int row = c >> 3, ch = c & 7;
        const uint4 o = *(const uint4*)&E[wave * 16 + row][ch * 8];
        *(uint4*)&AO[((size_t)b * 2048 + qw + row) * 2048 + h * 64 + ch * 8] = o;
    }
}

// ---------------------------------------------------------------- host
extern "C" void kernel_launch(void* const* d_in, const int* in_sizes, int n_in,
                              void* d_out, int out_size, void* d_ws, size_t ws_size,
                              hipStream_t stream) {
    const float* x  = (const float*)d_in[0];
    const float* fc = (const float*)d_in[1];
    const int* sid  = (const int*)d_in[2];
    const float* wq = (const float*)d_in[3];
    const float* wk = (const float*)d_in[4];
    const float* wv = (const float*)d_in[5];
    const float* wo = (const float*)d_in[6];
    float* out = (float*)d_out;

    unsigned short* xb   = (unsigned short*)d_ws;
    unsigned short* wqkv = xb + (size_t)4096 * 2048;
    unsigned short* wob  = wqkv + (size_t)3072 * 2048;
    unsigned short* Qb   = wob + (size_t)2048 * 2048;
    unsigned short* Kb   = Qb + (size_t)2 * 32 * 2048 * 64;
    unsigned short* Vb   = Kb + (size_t)2 * 8 * 2048 * 64;
    unsigned short* AO   = Vb + (size_t)2 * 8 * 2048 * 64;
    int* dstart = (int*)(AO + (size_t)4096 * 2048);

    cvt_all_kernel<<<18432, 256, 0, stream>>>(x, wq, wk, wv, wo, xb, wqkv, wob);
    docstart_kernel<<<16, 256, 0, stream>>>(sid, dstart);
    gemm_qkv8<<<dim3(256), 512, 0, stream>>>(xb, wqkv, Qb, Kb, Vb);
    rope_k_kernel<<<1024, 256, 0, stream>>>(Kb, fc);
    attn_kernel<<<dim3(16, 32, 2), 512, 0, stream>>>(Qb, Kb, Vb, dstart, fc, AO);
    gemm_bt<1><<<dim3(16, 32), 256, 0, stream>>>(AO, wob, 2048, 2048, nullptr, nullptr, nullptr, out);
}